// Round 19
// baseline (317.761 us; speedup 1.0000x reference)
//
#include <hip/hip_runtime.h>

static constexpr int Bc = 4, Tc = 1024, Sc = 1024, Dc = 1024, Hc = 16, DHc = 64, FFc = 4096;

typedef __attribute__((ext_vector_type(8))) short short8;
typedef __attribute__((ext_vector_type(4))) short short4v;
typedef __attribute__((ext_vector_type(4))) float f32x4;

struct P8 { unsigned short* o[8]; };

__device__ __forceinline__ unsigned short f2bf(float f) {
    unsigned int u = __float_as_uint(f);
    unsigned int r = u + 0x7fffu + ((u >> 16) & 1u);
    return (unsigned short)(r >> 16);
}
__device__ __forceinline__ float bf2f(unsigned short u) {
    return __uint_as_float(((unsigned int)u) << 16);
}
__device__ __forceinline__ float fexp2(float x) {
    float r; asm("v_exp_f32 %0, %1" : "=v"(r) : "v"(x)); return r;
}
__device__ __forceinline__ unsigned int cvtpk(float a, float b) {
    unsigned int r;
    asm("v_cvt_pk_bf16_f32 %0, %1, %2" : "=v"(r) : "v"(a), "v"(b));
    return r;
}

__device__ __forceinline__ void gload_lds16(const void* g, void* l) {
    __builtin_amdgcn_global_load_lds((const __attribute__((address_space(1))) void*)g,
                                     (__attribute__((address_space(3))) void*)l, 16, 0, 0);
}

// ---------------- cast f32 -> bf16 (two tensors in one launch) ----------------
__global__ __launch_bounds__(256) void cast2_f32_bf16(const float* __restrict__ inA,
                                                      const float* __restrict__ inB,
                                                      unsigned short* __restrict__ outA,
                                                      unsigned short* __restrict__ outB, int n8) {
    int i = blockIdx.x * 256 + threadIdx.x;
    if (i >= n8) return;
    const float* in = blockIdx.y ? inB : inA;
    unsigned short* out = blockIdx.y ? outB : outA;
    const float4* p = (const float4*)in + (size_t)i * 2;
    float4 a = p[0], b = p[1];
    short8 o;
    o[0] = f2bf(a.x); o[1] = f2bf(a.y); o[2] = f2bf(a.z); o[3] = f2bf(a.w);
    o[4] = f2bf(b.x); o[5] = f2bf(b.y); o[6] = f2bf(b.z); o[7] = f2bf(b.w);
    *(short8*)(out + (size_t)i * 8) = o;
}

// ---------------- unified weight transpose+cast: 16 jobs of 1024x1024 views ----------------
struct TJ { const float* s; unsigned short* d; int ss, ds; float scl; };
struct TJ16 { TJ j[16]; };
__global__ __launch_bounds__(256) void transpose_cast16(TJ16 p) {
    __shared__ float t[64][65];
    const TJ jb = p.j[blockIdx.z];
    const int c0 = blockIdx.x * 64, r0 = blockIdx.y * 64;
    const int tid = threadIdx.x;
    const int rr = tid >> 2, cc = (tid & 3) * 16;
    const float* src = jb.s + (size_t)(r0 + rr) * jb.ss + c0 + cc;
#pragma unroll
    for (int i = 0; i < 4; i++) {
        float4 v = *(const float4*)(src + i * 4);
        t[rr][cc + i * 4 + 0] = v.x;
        t[rr][cc + i * 4 + 1] = v.y;
        t[rr][cc + i * 4 + 2] = v.z;
        t[rr][cc + i * 4 + 3] = v.w;
    }
    __syncthreads();
#pragma unroll
    for (int half = 0; half < 2; half++) {
        const int id = half * 256 + tid;
        const int a = id >> 3, b0 = id & 7;
        short8 o;
#pragma unroll
        for (int e = 0; e < 8; e++) o[e] = f2bf(t[b0 * 8 + e][a] * jb.scl);
        *(short8*)(jb.d + (size_t)(c0 + a) * jb.ds + r0 + b0 * 8) = o;
    }
}

// ---------------- all bias prep in one launch (6144 elems) ----------------
__global__ void prep_bias(const float* dbq, const float* dbk, const float* dbv,
                          const float* ebk, const float* ebv, const float* ebq,
                          float* __restrict__ bqkv, float* __restrict__ bekv,
                          float* __restrict__ ebq_s, float SC) {
    int i = blockIdx.x * 256 + threadIdx.x;
    int seg = i >> 10, j = i & 1023;
    switch (seg) {
        case 0: bqkv[j] = dbq[j] * SC; break;
        case 1: bqkv[1024 + j] = dbk[j]; break;
        case 2: bqkv[2048 + j] = dbv[j]; break;
        case 3: bekv[j] = ebk[j]; break;
        case 4: bekv[1024 + j] = ebv[j]; break;
        default: ebq_s[j] = ebq[j] * SC; break;
    }
}

// ---- block remap: chunked-XCD + group-major rasterization (bijective, nwg%8==0) ----
struct BlkMap { int m, n, z; };
__device__ __forceinline__ BlkMap remap_block() {
    const int gx = gridDim.x, gy = gridDim.y;
    const int nxy = gx * gy;
    const int nwg = nxy * gridDim.z;
    const int flat = (blockIdx.z * gy + blockIdx.y) * gx + blockIdx.x;
    const int id = (flat & 7) * (nwg >> 3) + (flat >> 3);
    const int pz = id / nxy;
    const int rz = id - pz * nxy;
    const int gwsh = (gx & 7) ? 2 : 3;
    const int gw = 1 << gwsh;
    const int gsz = gw * gy;
    const int grp = rz / gsz;
    const int rem = rz - grp * gsz;
    BlkMap r;
    r.m = rem >> gwsh;
    r.n = (grp << gwsh) + (rem & (gw - 1));
    r.z = pz;
    return r;
}

// shared inner K-loop body (8-phase m201 schedule) for the fused QKV+eKV kernel
#define G256_BODY()                                                                            \
    stB(0, 0, 0); stA(0, 0, 0); stB(0, 1, 0); stA(0, 1, 0);                                    \
    stB(1, 0, 64); stA(1, 0, 64); stB(1, 1, 64);                                               \
    asm volatile("s_waitcnt vmcnt(6)" ::: "memory");                                           \
    __builtin_amdgcn_s_barrier();                                                              \
    const int nIter = nk >> 1;                                                                 \
    for (int it = 0; it < nIter; ++it) {                                                       \
        const int t_ = 2 * it, u_ = t_ + 1;                                                    \
        const int ku = u_ * 64;                                                                \
        const int kv = ((t_ + 2 < nk) ? t_ + 2 : t_) * 64;                                     \
        const int kw = ((u_ + 2 < nk) ? u_ + 2 : u_) * 64;                                     \
        ldB(0, 0, b0); ldA(0, 0, aF, aH);                                                      \
        stA(1, 1, ku);                                                                         \
        asm volatile("s_waitcnt lgkmcnt(8)" ::: "memory");                                     \
        __builtin_amdgcn_s_barrier();                                                          \
        asm volatile("s_waitcnt lgkmcnt(0)" ::: "memory");                                     \
        __builtin_amdgcn_s_setprio(1); MFMA16(aF, b0, 0); __builtin_amdgcn_s_setprio(0);       \
        __builtin_amdgcn_s_barrier();                                                          \
        ldB(0, 1, b1);                                                                         \
        stB(0, 0, kv);                                                                         \
        __builtin_amdgcn_s_barrier();                                                          \
        asm volatile("s_waitcnt lgkmcnt(0)" ::: "memory");                                     \
        __builtin_amdgcn_s_setprio(1); MFMA16(aH, b1, 0); __builtin_amdgcn_s_setprio(0);       \
        __builtin_amdgcn_s_barrier();                                                          \
        ldA(0, 1, aF, aH);                                                                     \
        stA(0, 0, kv);                                                                         \
        __builtin_amdgcn_s_barrier();                                                          \
        asm volatile("s_waitcnt lgkmcnt(0)" ::: "memory");                                     \
        __builtin_amdgcn_s_setprio(1); MFMA16(aH, b1, 4); __builtin_amdgcn_s_setprio(0);       \
        __builtin_amdgcn_s_barrier();                                                          \
        stB(0, 1, kv);                                                                         \
        __builtin_amdgcn_s_barrier();                                                          \
        __builtin_amdgcn_s_setprio(1); MFMA16(aF, b0, 4); __builtin_amdgcn_s_setprio(0);       \
        asm volatile("s_waitcnt vmcnt(6)" ::: "memory");                                       \
        __builtin_amdgcn_s_barrier();                                                          \
        ldB(1, 0, b0); ldA(1, 0, aF, aH);                                                      \
        stA(0, 1, kv);                                                                         \
        asm volatile("s_waitcnt lgkmcnt(8)" ::: "memory");                                     \
        __builtin_amdgcn_s_barrier();                                                          \
        asm volatile("s_waitcnt lgkmcnt(0)" ::: "memory");                                     \
        __builtin_amdgcn_s_setprio(1); MFMA16(aF, b0, 0); __builtin_amdgcn_s_setprio(0);       \
        __builtin_amdgcn_s_barrier();                                                          \
        ldB(1, 1, b1);                                                                         \
        stB(1, 0, kw);                                                                         \
        __builtin_amdgcn_s_barrier();                                                          \
        asm volatile("s_waitcnt lgkmcnt(0)" ::: "memory");                                     \
        __builtin_amdgcn_s_setprio(1); MFMA16(aH, b1, 0); __builtin_amdgcn_s_setprio(0);       \
        __builtin_amdgcn_s_barrier();                                                          \
        ldA(1, 1, aF, aH);                                                                     \
        stA(1, 0, kw);                                                                         \
        __builtin_amdgcn_s_barrier();                                                          \
        asm volatile("s_waitcnt lgkmcnt(0)" ::: "memory");                                     \
        __builtin_amdgcn_s_setprio(1); MFMA16(aH, b1, 4); __builtin_amdgcn_s_setprio(0);       \
        __builtin_amdgcn_s_barrier();                                                          \
        stB(1, 1, kw);                                                                         \
        __builtin_amdgcn_s_barrier();                                                          \
        __builtin_amdgcn_s_setprio(1); MFMA16(aF, b0, 4); __builtin_amdgcn_s_setprio(0);       \
        asm volatile("s_waitcnt vmcnt(6)" ::: "memory");                                       \
        __builtin_amdgcn_s_barrier();                                                          \
    }                                                                                          \
    asm volatile("s_waitcnt vmcnt(0)" ::: "memory");                                           \
    __syncthreads();

#define MFMA16(aa, bb, base)                                                                   \
    _Pragma("unroll") for (int m_ = 0; m_ < 4; m_++)                                           \
        _Pragma("unroll") for (int n_ = 0; n_ < 4; n_++)                                       \
            acc[(base) + m_][n_] = __builtin_amdgcn_mfma_f32_16x16x32_bf16(                    \
                (aa)[m_], (bb)[n_], acc[(base) + m_][n_], 0, 0, 0);

// ================= fused multi-job GEMM (QKV + eKV), 8-phase, runtime epilogue ==========
struct GJob {
    const unsigned short *A, *Bt;
    const float* bias;
    unsigned short *out, *vt;
    int N, lda, ldb, nk, vthresh, nwg, gx;
};
struct GJ2 { GJob j[2]; };
__global__ __launch_bounds__(512, 2) void gemm256j(GJ2 p) {
    __shared__ unsigned short SM[2][2][2][8192];
    const int tid = threadIdx.x;
    const int lane = tid & 63, wid = tid >> 6;
    const int l4 = lane & 15, g = lane >> 4;
    const int wr = wid >> 2, wc = wid & 3;

    int f = blockIdx.x;
    const int ji = (f < p.j[0].nwg) ? 0 : 1;
    if (ji) f -= p.j[0].nwg;
    const GJob jb = p.j[ji];
    const int id = (f & 7) * (jb.nwg >> 3) + (f >> 3);
    const int gwsh = (jb.gx & 7) ? 2 : 3;
    const int gw = 1 << gwsh;
    const int gy = jb.nwg / jb.gx;
    const int gsz = gw * gy;
    const int grp = id / gsz;
    const int rem = id - grp * gsz;
    const int m0 = (rem >> gwsh) * 256;
    const int n0 = ((grp << gwsh) + (rem & (gw - 1))) * 256;

    const unsigned short* A = jb.A;
    const unsigned short* Bt = jb.Bt;
    const int lda = jb.lda, ldb = jb.ldb, nk = jb.nk;
    const int sw = l4 & 7;

    const int fl0 = tid, fl1 = 512 + tid;
    const int lr0 = fl0 >> 3, ch0 = (fl0 & 7) ^ (lr0 & 7);
    const int lr1 = fl1 >> 3, ch1 = (fl1 & 7) ^ (lr1 & 7);
    const size_t A64 = (size_t)64 * lda;
    const unsigned short* pA0 = A + (size_t)(m0 + (lr0 >> 6) * 128 + (lr0 & 63)) * lda + ch0 * 8;
    const unsigned short* pA1 = A + (size_t)(m0 + (lr1 >> 6) * 128 + (lr1 & 63)) * lda + ch1 * 8;
    const unsigned short* pB0 = Bt + (size_t)(n0 + (ch0 >> 2) * 128 + lr0) * ldb + (ch0 & 3) * 8;
    const unsigned short* pB1 = Bt + (size_t)(n0 + (ch1 >> 2) * 128 + lr1) * ldb + (ch1 & 3) * 8;

    auto stA = [&](int d, int mh, int kofs) {
        char* base = (char*)&SM[0][d][mh][0];
        gload_lds16(pA0 + (size_t)mh * A64 + kofs, base + fl0 * 16);
        gload_lds16(pA1 + (size_t)mh * A64 + kofs, base + fl1 * 16);
    };
    auto stB = [&](int d, int ks, int kofs) {
        char* base = (char*)&SM[1][d][ks][0];
        gload_lds16(pB0 + ks * 32 + kofs, base + fl0 * 16);
        gload_lds16(pB1 + ks * 32 + kofs, base + fl1 * 16);
    };

    f32x4 acc[8][4] = {};
    short8 aF[4], aH[4], b0[4], b1[4];

    auto ldA = [&](int d, int mh, short8* d0, short8* d1) {
#pragma unroll
        for (int m = 0; m < 4; m++) {
            const char* rp = (const char*)&SM[0][d][mh][0] + (wr * 64 + m * 16 + l4) * 128;
            d0[m] = *(const short8*)(rp + ((g ^ sw) * 16));
            d1[m] = *(const short8*)(rp + (((4 + g) ^ sw) * 16));
        }
    };
    auto ldB = [&](int d, int ks, short8* dst) {
#pragma unroll
        for (int n = 0; n < 4; n++) {
            const char* rp = (const char*)&SM[1][d][ks][0] + ((wc & 1) * 64 + n * 16 + l4) * 128;
            dst[n] = *(const short8*)(rp + ((((wc >> 1) * 4 + g) ^ sw) * 16));
        }
    };

    G256_BODY()

    unsigned short* eb = (unsigned short*)SM;
    const int colL = wc * 64 + l4;
#pragma unroll
    for (int h = 0; h < 2; ++h) {
        if (wr == h) {
#pragma unroll
            for (int mm = 0; mm < 8; mm++) {
                const int base_r = (mm < 4 ? mm * 16 : 64 + (mm - 4) * 16) + g * 4;
#pragma unroll
                for (int n = 0; n < 4; n++) {
                    float bv = jb.bias[n0 + colL + n * 16];
#pragma unroll
                    for (int r = 0; r < 4; r++)
                        eb[(base_r + r) * 260 + colL + n * 16] = f2bf(acc[mm][n][r] + bv);
                }
            }
        }
        __syncthreads();
        const int gr0 = m0 + h * 128;
        if (n0 >= jb.vthresh) {
            const int b_ = gr0 >> 10, sb = gr0 & 1023;
#pragma unroll
            for (int j = 0; j < 4; j++) {
                const int id2 = j * 512 + tid;
                const int col = id2 & 255, rseg = id2 >> 8;
                const int rel = n0 - jb.vthresh + col;
                const int hh = rel >> 6, dh = rel & 63;
                short8 v0, v1;
#pragma unroll
                for (int e = 0; e < 8; e++) {
                    v0[e] = eb[(rseg * 16 + e) * 260 + col];
                    v1[e] = eb[(rseg * 16 + 8 + e) * 260 + col];
                }
                unsigned short* dp = jb.vt +
                    ((size_t)(b_ * 16 + hh) * 64 + dh) * 1024 + sb + rseg * 16;
                *(short8*)dp = v0;
                *(short8*)(dp + 8) = v1;
            }
        } else {
#pragma unroll
            for (int j = 0; j < 8; j++) {
                const int ff = j * 8192 + tid * 16;
                const int row = ff >> 9;
                const int colb = ff & 511;
                short8 v = *(const short8*)((const char*)eb + row * 520 + colb);
                *(short8*)(jb.out + (size_t)(gr0 + row) * jb.N + n0 + (colb >> 1)) = v;
            }
        }
        if (h == 0) __syncthreads();
    }
}

// ======== GEMM 128x256, BK=32, dbuf, 2-phase, occupancy-2 (FFN path) ==========
// EPI: 2 = relu+bf16; 3 = bf16 split-K partial to po.o[z] (bias only z==0)
template <int EPI>
__global__ __launch_bounds__(512, 4) void gemm128x256(const unsigned short* __restrict__ A,
                                                      const unsigned short* __restrict__ Bt,
                                                      const float* __restrict__ bias,
                                                      unsigned short* __restrict__ outB,
                                                      int N, int lda, int ldb, int nk, P8 po) {
    __shared__ unsigned short SMEM[24576];   // 48KB: As 2x4096, Bs 2x8192
    unsigned short* As0 = SMEM;
    unsigned short* As1 = SMEM + 4096;
    unsigned short* Bs0 = SMEM + 8192;
    unsigned short* Bs1 = SMEM + 16384;
    const int tid = threadIdx.x;
    const int lane = tid & 63, wid = tid >> 6;
    const int l4 = lane & 15, g = lane >> 4;
    const int wr = wid >> 2, wc = wid & 3;   // 2x4 waves; per-wave out 64x64
    BlkMap bm = remap_block();
    const int m0 = bm.m * 128, n0 = bm.n * 256, z = bm.z;
    A += (size_t)z * (nk * 32);
    Bt += (size_t)z * (nk * 32);

    // staging: A 512 slots (1/thread), B 1024 slots (2/thread); chunk=(s&3)^(row&3)
    const int ra = tid >> 2, ca = (tid & 3) ^ (ra & 3);
    const int sb1 = 512 + tid;
    const int rb0 = tid >> 2, cb0 = (tid & 3) ^ (rb0 & 3);
    const int rb1 = sb1 >> 2, cb1 = (sb1 & 3) ^ (rb1 & 3);
    const unsigned short* pA = A + (size_t)(m0 + ra) * lda + ca * 8;
    const unsigned short* pB0 = Bt + (size_t)(n0 + rb0) * ldb + cb0 * 8;
    const unsigned short* pB1 = Bt + (size_t)(n0 + rb1) * ldb + cb1 * 8;
    auto stage = [&](int d, int kofs) {
        gload_lds16(pA + kofs, (char*)(d ? As1 : As0) + tid * 16);
        gload_lds16(pB0 + kofs, (char*)(d ? Bs1 : Bs0) + tid * 16);
        gload_lds16(pB1 + kofs, (char*)(d ? Bs1 : Bs0) + sb1 * 16);
    };

    f32x4 acc[4][4] = {};
    stage(0, 0);
    if (nk > 1) stage(1, 32);
    asm volatile("s_waitcnt vmcnt(3)" ::: "memory");
    __builtin_amdgcn_s_barrier();

    for (int t = 0; t < nk; ++t) {
        const int cur = t & 1;
        const unsigned short* Asr = cur ? As1 : As0;
        const unsigned short* Bsr = cur ? Bs1 : Bs0;
        short8 a[4], b[4];
#pragma unroll
        for (int m = 0; m < 4; m++) {
            const int row = wr * 64 + m * 16 + l4;
            a[m] = *(const short8*)(Asr + row * 32 + ((g ^ (row & 3)) * 8));
        }
#pragma unroll
        for (int n = 0; n < 4; n++) {
            const int row = wc * 64 + n * 16 + l4;
            b[n] = *(const short8*)(Bsr + row * 32 + ((g ^ (row & 3)) * 8));
        }
        asm volatile("s_waitcnt lgkmcnt(0)" ::: "memory");
        __builtin_amdgcn_sched_barrier(0);
        __builtin_amdgcn_s_barrier();     // all frag reads done -> cur buffer reusable
        if (t + 2 < nk) stage(cur, (t + 2) * 32);
        __builtin_amdgcn_s_setprio(1);
#pragma unroll
        for (int m = 0; m < 4; m++)
#pragma unroll
            for (int n = 0; n < 4; n++)
                acc[m][n] = __builtin_amdgcn_mfma_f32_16x16x32_bf16(a[m], b[n], acc[m][n], 0, 0, 0);
        __builtin_amdgcn_s_setprio(0);
        if (t + 1 < nk) {
            if (t + 2 < nk) asm volatile("s_waitcnt vmcnt(3)" ::: "memory");
            else            asm volatile("s_waitcnt vmcnt(0)" ::: "memory");
            __builtin_amdgcn_s_barrier();
        }
    }
    __syncthreads();

    // coalesced epilogue via LDS (64-row halves; eb = 64x260 shorts = 33KB)
    unsigned short* eb = SMEM;
    unsigned short* oB = (EPI == 3) ? po.o[z] : outB;
    const int colL = wc * 64 + l4;
#pragma unroll
    for (int h = 0; h < 2; ++h) {
        if (wr == h) {
#pragma unroll
            for (int mm = 0; mm < 4; mm++) {
                const int lr = mm * 16 + g * 4;
#pragma unroll
                for (int n = 0; n < 4; n++) {
                    float bv = (EPI == 3 && z != 0) ? 0.f : bias[n0 + colL + n * 16];
#pragma unroll
                    for (int r = 0; r < 4; r++) {
                        float v = acc[mm][n][r] + bv;
                        if (EPI == 2) v = fmaxf(v, 0.f);
                        eb[(lr + r) * 260 + colL + n * 16] = f2bf(v);
                    }
                }
            }
        }
        __syncthreads();
        const int gr0 = m0 + h * 64;
#pragma unroll
        for (int j = 0; j < 4; j++) {
            const int id2 = j * 512 + tid;
            const int row = id2 >> 5, c8 = (id2 & 31) * 8;
            short8 v = *(const short8*)(eb + row * 260 + c8);
            *(short8*)(oB + (size_t)(gr0 + row) * N + n0 + c8) = v;
        }
        if (h == 0) __syncthreads();
    }
}

// ---------------- GEMM 64x128: 3-buffer depth-2, counted vmcnt, XCD-swizzled ----------------
template <int EPI>
__global__ __launch_bounds__(256) void gemm64_db(const unsigned short* __restrict__ A,
                                                 const unsigned short* __restrict__ Bt,
                                                 const float* __restrict__ bias,
                                                 float* __restrict__ outF,
                                                 unsigned short* __restrict__ outB,
                                                 int M, int N, int Kloop, int lda, int ldb) {
    __shared__ unsigned short As[3][64 * 32];
    __shared__ unsigned short Bs[3][128 * 32];
    const int tid = threadIdx.x;
    const int w = tid >> 6, lane = tid & 63, l4 = lane & 15, g = lane >> 4;
    BlkMap bm = remap_block();
    const int m0 = bm.m * 64, n0 = bm.n * 128;
    f32x4 acc[4][2] = {};
    const int r0 = tid >> 2;
    const int kk = ((tid & 3) ^ ((tid >> 3) & 3)) * 8;
    const int sk = (l4 >> 1) & 3;
    const unsigned short* Ar0 = A + (size_t)(m0 + r0) * lda + kk;
    const unsigned short* Br0 = Bt + (size_t)(n0 + r0) * ldb + kk;
    const unsigned short* Br1 = Bt + (size_t)(n0 + 64 + r0) * ldb + kk;
    auto stage = [&](int sb, int k0) {
        gload_lds16(Ar0 + k0, (char*)As[sb] + tid * 16);
        gload_lds16(Br0 + k0, (char*)Bs[sb] + tid * 16);
        gload_lds16(Br1 + k0, (char*)Bs[sb] + 4096 + tid * 16);
    };
    const int nk = Kloop >> 5;
    stage(0, 0);
    stage(1, 32);
    asm volatile("s_waitcnt vmcnt(3)" ::: "memory");
    __builtin_amdgcn_s_barrier();
    asm volatile("" ::: "memory");
    int buf = 0;
    for (int t = 0; t < nk; ++t) {
        if (t + 2 < nk) {
            int b2 = buf + 2; if (b2 >= 3) b2 -= 3;
            stage(b2, (t + 2) * 32);
        }
        short8 a[4], b[2];
#pragma unroll
        for (int m = 0; m < 4; m++)
            a[m] = *(const short8*)(As[buf] + (m * 16 + l4) * 32 + (g ^ sk) * 8);
#pragma unroll
        for (int n = 0; n < 2; n++)
            b[n] = *(const short8*)(Bs[buf] + (w * 32 + n * 16 + l4) * 32 + (g ^ sk) * 8);
#pragma unroll
        for (int m = 0; m < 4; m++)
#pragma unroll
            for (int n = 0; n < 2; n++)
                acc[m][n] = __builtin_amdgcn_mfma_f32_16x16x32_bf16(a[m], b[n], acc[m][n], 0, 0, 0);
        if (t + 1 < nk) {
            if (t + 2 < nk) asm volatile("s_waitcnt vmcnt(3)" ::: "memory");
            else            asm volatile("s_waitcnt vmcnt(0)" ::: "memory");
            __builtin_amdgcn_s_barrier();
            asm volatile("" ::: "memory");
        }
        buf = (buf + 1 == 3) ? 0 : buf + 1;
    }
    const int rowB = m0 + g * 4;
    const int colB = n0 + w * 32 + l4;
#pragma unroll
    for (int n = 0; n < 2; n++) {
        float bv = bias[colB + n * 16];
#pragma unroll
        for (int m = 0; m < 4; m++) {
#pragma unroll
            for (int r = 0; r < 4; r++) {
                float v = acc[m][n][r] + bv;
                if (EPI == 2) v = fmaxf(v, 0.f);
                size_t idx = (size_t)(rowB + m * 16 + r) * N + colB + n * 16;
                if (EPI == 1) outF[idx] = v;
                else outB[idx] = f2bf(v);
            }
        }
    }
}

// ---------------- flash attention v6: 8 waves / 128 q-rows per block ----------------
template <int CAUSAL>
__global__ __launch_bounds__(512) void attn6_kernel(const unsigned short* __restrict__ Q, int ldq,
                                                    const unsigned short* __restrict__ Kg, int ldk,
                                                    const unsigned short* __restrict__ Vt,
                                                    unsigned short* __restrict__ O) {
    __shared__ unsigned short Kl[2 * 64 * 64];
    __shared__ unsigned short Vl[2 * 64 * 64];
    __shared__ unsigned short Pl[8][16 * 72];
    const int bh = blockIdx.x;
    const int qb = CAUSAL ? (gridDim.y - 1 - blockIdx.y) : blockIdx.y;
    const int b = bh >> 4, h = bh & 15;
    const int tid = threadIdx.x, w = tid >> 6, lane = tid & 63;
    const int l4 = lane & 15, g = lane >> 4;
    const int q0 = qb * 128 + w * 16;
    const unsigned short* Qp = Q + (size_t)(b * Tc + q0 + l4) * ldq + h * DHc + g * 8;
    short8 qf0 = *(const short8*)Qp;
    short8 qf1 = *(const short8*)(Qp + 32);
    const unsigned short* Kbase = Kg + (size_t)(b * 1024) * ldk + h * DHc;
    const unsigned short* Vbase = Vt + (size_t)bh * DHc * 1024;
    f32x4 o[4] = {};
    float mrun = -1e30f, lrun = 0.f;
    const int nT = CAUSAL ? 2 * qb + 2 : 16;
    unsigned short* pw = &Pl[w][l4 * 72];
    const int qi = q0 + l4;

    short8 ones;
#pragma unroll
    for (int j = 0; j < 8; j++) ones[j] = (short)0x3F80;

    const int sr = tid >> 3;
    const int sc_ = (tid & 7) ^ (sr & 7);

    auto stage = [&](int s0, int buf) {
        char* kd = (char*)Kl + buf * 8192;
        char* vd = (char*)Vl + buf * 8192;
        gload_lds16(Kbase + (size_t)(s0 + sr) * ldk + sc_ * 8, kd + tid * 16);
        gload_lds16(Vbase + (size_t)sr * 1024 + s0 + sc_ * 8, vd + tid * 16);
    };

    stage(0, 0);
    __syncthreads();
    int buf = 0;
    const int sw = l4 & 7;

    for (int t = 0; t < nT; ++t) {
        const int s0 = t * 64;
        if (t + 1 < nT) stage(s0 + 64, buf ^ 1);
        if (!CAUSAL || s0 <= q0 + 15) {
            const unsigned short* Kb_ = Kl + buf * 4096;
            const unsigned short* Vb_ = Vl + buf * 4096;
            f32x4 st[4];
            f32x4 z = {0.f, 0.f, 0.f, 0.f};
            __builtin_amdgcn_s_setprio(1);
#pragma unroll
            for (int c = 0; c < 4; c++) {
                const unsigned short* kr = Kb_ + (c * 16 + l4) * 64;
                short8 ka0 = *(const short8*)(kr + ((g ^ sw) * 8));
                short8 ka1 = *(const short8*)(kr + (((g + 4) ^ sw) * 8));
                st[c] = __builtin_amdgcn_mfma_f32_16x16x32_bf16(ka0, qf0, z, 0, 0, 0);
                st[c] = __builtin_amdgcn_mfma_f32_16x16x32_bf16(ka1, qf1, st[c], 0, 0, 0);
            }
            __builtin_amdgcn_s_setprio(0);
            float p[16];
            const bool domask = CAUSAL && (s0 + 63 > q0);
#pragma unroll
            for (int c = 0; c < 4; c++)
#pragma unroll
                for (int r = 0; r < 4; r++) {
                    float v = st[c][r];
                    if (domask && (s0 + c * 16 + g * 4 + r) > qi) v = -1e9f;
                    p[c * 4 + r] = v;
                }
            float m1 = fmaxf(fmaxf(p[0], p[1]), p[2]);
            float m2 = fmaxf(fmaxf(p[3], p[4]), p[5]);
            float m3 = fmaxf(fmaxf(p[6], p[7]), p[8]);
            float m4 = fmaxf(fmaxf(p[9], p[10]), p[11]);
            float m5 = fmaxf(fmaxf(p[12], p[13]), p[14]);
            float tmax = fmaxf(fmaxf(fmaxf(m1, m2), fmaxf(m3, m4)), fmaxf(m5, p[15]));
            tmax = fmaxf(tmax, __shfl_xor(tmax, 16));
            tmax = fmaxf(tmax, __shfl_xor(tmax, 32));
            if (!__all(tmax <= mrun + 11.5f)) {
                float mnew = fmaxf(mrun, tmax);
                float al = fexp2(mrun - mnew);
                lrun *= al;
#pragma unroll
                for (int d = 0; d < 4; d++) o[d] *= al;
                mrun = mnew;
            }
#pragma unroll
            for (int i = 0; i < 16; i++) p[i] = fexp2(p[i] - mrun);
#pragma unroll
            for (int c = 0; c < 4; c++) {
                uint2 u;
                u.x = cvtpk(p[c * 4 + 0], p[c * 4 + 1]);
                u.y = cvtpk(p[c * 4 + 2], p[c * 4 + 3]);
                *(uint2*)(pw + c * 16 + g * 4) = u;
            }
            short8 pb_lo = *(const short8*)(pw + g * 8);
            short8 pb_hi = *(const short8*)(pw + 32 + g * 8);
            __builtin_amdgcn_s_setprio(1);
            f32x4 s4 = __builtin_amdgcn_mfma_f32_16x16x32_bf16(ones, pb_lo, z, 0, 0, 0);
            s4 = __builtin_amdgcn_mfma_f32_16x16x32_bf16(ones, pb_hi, s4, 0, 0, 0);
#pragma unroll
            for (int d = 0; d < 4; d++) {
                const unsigned short* vr = Vb_ + (d * 16 + l4) * 64;
                short8 va0 = *(const short8*)(vr + ((g ^ sw) * 8));
                short8 va1 = *(const short8*)(vr + (((g + 4) ^ sw) * 8));
                o[d] = __builtin_amdgcn_mfma_f32_16x16x32_bf16(va0, pb_lo, o[d], 0, 0, 0);
                o[d] = __builtin_amdgcn_mfma_f32_16x16x32_bf16(va1, pb_hi, o[d], 0, 0, 0);
            }
            __builtin_amdgcn_s_setprio(0);
            lrun += s4[0];
        }
        __syncthreads();
        buf ^= 1;
    }
    float inv = 1.f / lrun;
    unsigned short* Ob = O + (size_t)(b * Tc + q0 + l4) * Dc + h * DHc;
#pragma unroll
    for (int d = 0; d < 4; d++) {
#pragma unroll
        for (int r = 0; r < 4; r++) Ob[d * 16 + g * 4 + r] = f2bf(o[d][r] * inv);
    }
}

// ---------------- fused residual-add + LayerNorm (bf16 a + bf16 res) ----------------
__global__ __launch_bounds__(256) void ln_bf(const unsigned short* __restrict__ a,
                                             const unsigned short* __restrict__ res,
                                             const float* __restrict__ gam,
                                             const float* __restrict__ bet,
                                             unsigned short* __restrict__ outB,
                                             float* __restrict__ outF) {
    int row = blockIdx.x, t = threadIdx.x;
    size_t base = (size_t)row * Dc + t * 4;
    short4v av = *(const short4v*)(a + base);
    short4v rv = *(const short4v*)(res + base);
    float x0 = bf2f((unsigned short)av[0]) + bf2f((unsigned short)rv[0]);
    float x1 = bf2f((unsigned short)av[1]) + bf2f((unsigned short)rv[1]);
    float x2 = bf2f((unsigned short)av[2]) + bf2f((unsigned short)rv[2]);
    float x3 = bf2f((unsigned short)av[3]) + bf2f((unsigned short)rv[3]);
    float s = x0 + x1 + x2 + x3;
    float ss = x0 * x0 + x1 * x1 + x2 * x2 + x3 * x3;
    for (int o = 1; o < 64; o <<= 1) { s += __shfl_xor(s, o); ss += __shfl_xor(ss, o); }
    __shared__ float S1[4], S2[4];
    int w = t >> 6;
    if ((t & 63) == 0) { S1[w] = s; S2[w] = ss; }
    __syncthreads();
    s = S1[0] + S1[1] + S1[2] + S1[3];
    ss = S2[0] + S2[1] + S2[2] + S2[3];
    float mean = s * (1.f / Dc);
    float var = ss * (1.f / Dc) - mean * mean;
    float rstd = rsqrtf(var + 1e-5f);
    int c = t * 4;
    float4 g4 = *(const float4*)(gam + c);
    float4 b4 = *(const float4*)(bet + c);
    float y0 = (x0 - mean) * rstd * g4.x + b4.x;
    float y1 = (x1 - mean) * rstd * g4.y + b4.y;
    float y2 = (x2 - mean) * rstd * g4.z + b4.z;
    float y3 = (x3 - mean) * rstd * g4.w + b4.w;
    if (outB) {
        short4v ob;
        ob[0] = f2bf(y0); ob[1] = f2bf(y1); ob[2] = f2bf(y2); ob[3] = f2bf(y3);
        *(short4v*)(outB + base) = ob;
    }
    if (outF) { float4 ov = {y0, y1, y2, y3}; *(float4*)(outF + base) = ov; }
}

// ---------------- LN over 4 bf16 split-K partials + bf16 residual -> f32 out ----------------
__global__ __launch_bounds__(256) void ln_4b(const unsigned short* __restrict__ p,
                                             const unsigned short* __restrict__ res,
                                             const float* __restrict__ gam,
                                             const float* __restrict__ bet,
                                             float* __restrict__ outF) {
    const size_t PS = (size_t)4096 * 1024;
    int row = blockIdx.x, t = threadIdx.x;
    size_t base = (size_t)row * Dc + t * 4;
    float x0, x1, x2, x3;
    {
        short4v rv = *(const short4v*)(res + base);
        x0 = bf2f((unsigned short)rv[0]); x1 = bf2f((unsigned short)rv[1]);
        x2 = bf2f((unsigned short)rv[2]); x3 = bf2f((unsigned short)rv[3]);
    }
#pragma unroll
    for (int j = 0; j < 4; j++) {
        short4v v = *(const short4v*)(p + j * PS + base);
        x0 += bf2f((unsigned short)v[0]); x1 += bf2f((unsigned short)v[1]);
        x2 += bf2f((unsigned short)v[2]); x3 += bf2f((unsigned short)v[3]);
    }
    float s = x0 + x1 + x2 + x3;
    float ss = x0 * x0 + x1 * x1 + x2 * x2 + x3 * x3;
    for (int o = 1; o < 64; o <<= 1) { s += __shfl_xor(s, o); ss += __shfl_xor(ss, o); }
    __shared__ float S1[4], S2[4];
    int w = t >> 6;
    if ((t & 63) == 0) { S1[w] = s; S2[w] = ss; }
    __syncthreads();
    s = S1[0] + S1[1] + S1[2] + S1[3];
    ss = S2[0] + S2[1] + S2[2] + S2[3];
    float mean = s * (1.f / Dc);
    float var = ss * (1.f / Dc) - mean * mean;
    float rstd = rsqrtf(var + 1e-5f);
    int c = t * 4;
    float4 g4 = *(const float4*)(gam + c);
    float4 b4 = *(const float4*)(bet + c);
    float4 ov;
    ov.x = (x0 - mean) * rstd * g4.x + b4.x;
    ov.y = (x1 - mean) * rstd * g4.y + b4.y;
    ov.z = (x2 - mean) * rstd * g4.z + b4.z;
    ov.w = (x3 - mean) * rstd * g4.w + b4.w;
    *(float4*)(outF + base) = ov;
}

// ---------------- launch ----------------
extern "C" void kernel_launch(void* const* d_in, const int* in_sizes, int n_in,
                              void* d_out, int out_size, void* d_ws, size_t ws_size,
                              hipStream_t stream) {
    const float* x   = (const float*)d_in[0];
    const float* enc = (const float*)d_in[1];
    const float* dWq = (const float*)d_in[4];  const float* dbq = (const float*)d_in[5];
    const float* dWk = (const float*)d_in[6];  const float* dbk = (const float*)d_in[7];
    const float* dWv = (const float*)d_in[8];  const float* dbv = (const float*)d_in[9];
    const float* dWo = (const float*)d_in[10]; const float* dbo = (const float*)d_in[11];
    const float* eWq = (const float*)d_in[12]; const float* ebq = (const float*)d_in[13];
    const float* eWk = (const float*)d_in[14]; const float* ebk = (const float*)d_in[15];
    const float* eWv = (const float*)d_in[16]; const float* ebv = (const float*)d_in[17];
    const float* eWo = (const float*)d_in[18]; const float* ebo = (const float*)d_in[19];
    const float* fW1 = (const float*)d_in[20]; const float* fb1 = (const float*)d_in[21];
    const float* fW2 = (const float*)d_in[22]; const float* fb2 = (const float*)d_in[23];
    const float* g1 = (const float*)d_in[24];  const float* be1 = (const float*)d_in[25];
    const float* g2 = (const float*)d_in[26];  const float* be2 = (const float*)d_in[27];
    const float* g3 = (const float*)d_in[28];  const float* be3 = (const float*)d_in[29];

    const float SC = 0.125f * 1.44269504f;

    char* ws = (char*)d_ws;
    size_t off = 0;
    auto alloc = [&](size_t bytes) -> void* {
        void* p = ws + off;
        off += (bytes + 255) & ~(size_t)255;
        return p;
    };
    const size_t A = (size_t)4096 * 1024;
    const size_t MB1 = (size_t)1024 * 1024;
    char* R1 = (char*)alloc(32 * 1024 * 1024);
    unsigned short* qkv = (unsigned short*)R1;                       // stride 3072 (Q,K cols only)
    unsigned short* qx  = (unsigned short*)(R1 + 16 * 1024 * 1024);  // stride 1024
    unsigned short* h1  = (unsigned short*)R1;                       // 4096x4096
    unsigned short* xb   = (unsigned short*)alloc(A * 2);
    unsigned short* encb = (unsigned short*)alloc(A * 2);
    unsigned short* wqkv = (unsigned short*)alloc(3 * MB1 * 2);
    unsigned short* wekv = (unsigned short*)alloc(2 * MB1 * 2);
    unsigned short* weq  = (unsigned short*)alloc(MB1 * 2);
    unsigned short* wdo  = (unsigned short*)alloc(MB1 * 2);
    unsigned short* weo  = (unsigned short*)alloc(MB1 * 2);
    unsigned short* wf1  = (unsigned short*)alloc(4 * MB1 * 2);
    unsigned short* wf2  = (unsigned short*)alloc(4 * MB1 * 2);
    float* bqkv = (float*)alloc(3072 * 4);
    float* bekv = (float*)alloc(2048 * 4);
    float* ebq_s = (float*)alloc(1024 * 4);
    unsigned short* VtB = (unsigned short*)alloc(A * 2);
    unsigned short* ab  = (unsigned short*)alloc(A * 2);
    unsigned short* tmpB = (unsigned short*)alloc(A * 2);
    unsigned short* dB = (unsigned short*)alloc(A * 2);
    unsigned short* fB = (unsigned short*)alloc(A * 2);
    unsigned short* kb  = (unsigned short*)alloc(A * 2);   // cross-K rows (stride 1024)
    unsigned short* vtc = (unsigned short*)alloc(A * 2);   // cross V^T
    unsigned short* pfb = VtB;                             // FFN2 partials alias VtB..dB
    (void)ws_size; (void)in_sizes; (void)n_in; (void)out_size;

    cast2_f32_bf16<<<dim3(2048, 2), 256, 0, stream>>>(x, enc, xb, encb, (int)(A / 8));

    TJ16 tj;
    tj.j[0] = {dWq, wqkv,           1024, 1024, SC};
    tj.j[1] = {dWk, wqkv + MB1,     1024, 1024, 1.f};
    tj.j[2] = {dWv, wqkv + 2 * MB1, 1024, 1024, 1.f};
    tj.j[3] = {eWk, wekv,           1024, 1024, 1.f};
    tj.j[4] = {eWv, wekv + MB1,     1024, 1024, 1.f};
    tj.j[5] = {eWq, weq,            1024, 1024, SC};
    tj.j[6] = {dWo, wdo,            1024, 1024, 1.f};
    tj.j[7] = {eWo, weo,            1024, 1024, 1.f};
    for (int jj = 0; jj < 4; jj++) {
        tj.j[8 + jj]  = {fW1 + 1024 * jj, wf1 + (size_t)1024 * jj * 1024, 4096, 1024, 1.f};
        tj.j[12 + jj] = {fW2 + (size_t)1024 * jj * 1024, wf2 + 1024 * jj, 1024, 4096, 1.f};
    }
    transpose_cast16<<<dim3(16, 16, 16), 256, 0, stream>>>(tj);
    prep_bias<<<24, 256, 0, stream>>>(dbq, dbk, dbv, ebk, ebv, ebq, bqkv, bekv, ebq_s, SC);

    P8 z8{};

    // ---- fused QKV + eKV dispatch (320 blocks) ----
    {
        GJ2 gj;
        gj.j[0] = {xb, wqkv, bqkv, qkv, VtB, 3072, 1024, 1024, 16, 2048, 192, 12};
        gj.j[1] = {encb, wekv, bekv, kb, vtc, 1024, 1024, 1024, 16, 1024, 128, 8};
        gemm256j<<<dim3(320), 512, 0, stream>>>(gj);
    }

    // ---- self-attention block ----
    attn6_kernel<1><<<dim3(64, 8), 512, 0, stream>>>(qkv, 3072, qkv + 1024, 3072, VtB, ab);
    gemm64_db<0><<<dim3(8, 64), 256, 0, stream>>>(ab, wdo, dbo, nullptr, tmpB, 4096, 1024, 1024, 1024, 1024);
    ln_bf<<<4096, 256, 0, stream>>>(tmpB, xb, g1, be1, dB, nullptr);

    // ---- cross-attention block ----
    gemm64_db<0><<<dim3(8, 64), 256, 0, stream>>>(dB, weq, ebq_s, nullptr, qx, 4096, 1024, 1024, 1024, 1024);
    attn6_kernel<0><<<dim3(64, 8), 512, 0, stream>>>(qx, 1024, kb, 1024, vtc, ab);
    gemm64_db<0><<<dim3(8, 64), 256, 0, stream>>>(ab, weo, ebo, nullptr, tmpB, 4096, 1024, 1024, 1024, 1024);
    ln_bf<<<4096, 256, 0, stream>>>(tmpB, dB, g2, be2, fB, nullptr);

    // ---- FFN block (occupancy-2 128x256 kernel) ----
    gemm128x256<2><<<dim3(16, 32), 512, 0, stream>>>(fB, wf1, fb1, h1, 4096, 1024, 1024, 32, z8);
    {
        P8 pf{};
        pf.o[0] = pfb;
        pf.o[1] = pfb + A;
        pf.o[2] = pfb + 2 * A;
        pf.o[3] = pfb + 3 * A;
        gemm128x256<3><<<dim3(4, 32, 4), 512, 0, stream>>>(h1, wf2, fb2, nullptr, 1024, 4096, 4096, 32, pf);
    }
    ln_4b<<<4096, 256, 0, stream>>>(pfb, fB, g3, be3, (float*)d_out);
}

// Round 20
// 313.786 us; speedup vs baseline: 1.0127x; 1.0127x over previous
//
#include <hip/hip_runtime.h>

static constexpr int Bc = 4, Tc = 1024, Sc = 1024, Dc = 1024, Hc = 16, DHc = 64, FFc = 4096;

typedef __attribute__((ext_vector_type(8))) short short8;
typedef __attribute__((ext_vector_type(4))) short short4v;
typedef __attribute__((ext_vector_type(4))) float f32x4;

struct P8 { unsigned short* o[8]; };

__device__ __forceinline__ unsigned short f2bf(float f) {
    unsigned int u = __float_as_uint(f);
    unsigned int r = u + 0x7fffu + ((u >> 16) & 1u);
    return (unsigned short)(r >> 16);
}
__device__ __forceinline__ float bf2f(unsigned short u) {
    return __uint_as_float(((unsigned int)u) << 16);
}
__device__ __forceinline__ float fexp2(float x) {
    float r; asm("v_exp_f32 %0, %1" : "=v"(r) : "v"(x)); return r;
}
__device__ __forceinline__ unsigned int cvtpk(float a, float b) {
    unsigned int r;
    asm("v_cvt_pk_bf16_f32 %0, %1, %2" : "=v"(r) : "v"(a), "v"(b));
    return r;
}

__device__ __forceinline__ void gload_lds16(const void* g, void* l) {
    __builtin_amdgcn_global_load_lds((const __attribute__((address_space(1))) void*)g,
                                     (__attribute__((address_space(3))) void*)l, 16, 0, 0);
}

// ---------------- cast f32 -> bf16 (two tensors in one launch) ----------------
__global__ __launch_bounds__(256) void cast2_f32_bf16(const float* __restrict__ inA,
                                                      const float* __restrict__ inB,
                                                      unsigned short* __restrict__ outA,
                                                      unsigned short* __restrict__ outB, int n8) {
    int i = blockIdx.x * 256 + threadIdx.x;
    if (i >= n8) return;
    const float* in = blockIdx.y ? inB : inA;
    unsigned short* out = blockIdx.y ? outB : outA;
    const float4* p = (const float4*)in + (size_t)i * 2;
    float4 a = p[0], b = p[1];
    short8 o;
    o[0] = f2bf(a.x); o[1] = f2bf(a.y); o[2] = f2bf(a.z); o[3] = f2bf(a.w);
    o[4] = f2bf(b.x); o[5] = f2bf(b.y); o[6] = f2bf(b.z); o[7] = f2bf(b.w);
    *(short8*)(out + (size_t)i * 8) = o;
}

// ---------------- unified weight transpose+cast: 16 jobs of 1024x1024 views ----------------
struct TJ { const float* s; unsigned short* d; int ss, ds; float scl; };
struct TJ16 { TJ j[16]; };
__global__ __launch_bounds__(256) void transpose_cast16(TJ16 p) {
    __shared__ float t[64][65];
    const TJ jb = p.j[blockIdx.z];
    const int c0 = blockIdx.x * 64, r0 = blockIdx.y * 64;
    const int tid = threadIdx.x;
    const int rr = tid >> 2, cc = (tid & 3) * 16;
    const float* src = jb.s + (size_t)(r0 + rr) * jb.ss + c0 + cc;
#pragma unroll
    for (int i = 0; i < 4; i++) {
        float4 v = *(const float4*)(src + i * 4);
        t[rr][cc + i * 4 + 0] = v.x;
        t[rr][cc + i * 4 + 1] = v.y;
        t[rr][cc + i * 4 + 2] = v.z;
        t[rr][cc + i * 4 + 3] = v.w;
    }
    __syncthreads();
#pragma unroll
    for (int half = 0; half < 2; half++) {
        const int id = half * 256 + tid;
        const int a = id >> 3, b0 = id & 7;
        short8 o;
#pragma unroll
        for (int e = 0; e < 8; e++) o[e] = f2bf(t[b0 * 8 + e][a] * jb.scl);
        *(short8*)(jb.d + (size_t)(c0 + a) * jb.ds + r0 + b0 * 8) = o;
    }
}

// ---------------- all bias prep in one launch (6144 elems) ----------------
__global__ void prep_bias(const float* dbq, const float* dbk, const float* dbv,
                          const float* ebk, const float* ebv, const float* ebq,
                          float* __restrict__ bqkv, float* __restrict__ bekv,
                          float* __restrict__ ebq_s, float SC) {
    int i = blockIdx.x * 256 + threadIdx.x;
    int seg = i >> 10, j = i & 1023;
    switch (seg) {
        case 0: bqkv[j] = dbq[j] * SC; break;
        case 1: bqkv[1024 + j] = dbk[j]; break;
        case 2: bqkv[2048 + j] = dbv[j]; break;
        case 3: bekv[j] = ebk[j]; break;
        case 4: bekv[1024 + j] = ebv[j]; break;
        default: ebq_s[j] = ebq[j] * SC; break;
    }
}

// ---- block remap: chunked-XCD + group-major rasterization (bijective, nwg%8==0) ----
struct BlkMap { int m, n, z; };
__device__ __forceinline__ BlkMap remap_block() {
    const int gx = gridDim.x, gy = gridDim.y;
    const int nxy = gx * gy;
    const int nwg = nxy * gridDim.z;
    const int flat = (blockIdx.z * gy + blockIdx.y) * gx + blockIdx.x;
    const int id = (flat & 7) * (nwg >> 3) + (flat >> 3);
    const int pz = id / nxy;
    const int rz = id - pz * nxy;
    const int gwsh = (gx & 7) ? 2 : 3;
    const int gw = 1 << gwsh;
    const int gsz = gw * gy;
    const int grp = rz / gsz;
    const int rem = rz - grp * gsz;
    BlkMap r;
    r.m = rem >> gwsh;
    r.n = (grp << gwsh) + (rem & (gw - 1));
    r.z = pz;
    return r;
}

// shared inner K-loop body (8-phase m201 schedule)
#define G256_BODY()                                                                            \
    stB(0, 0, 0); stA(0, 0, 0); stB(0, 1, 0); stA(0, 1, 0);                                    \
    stB(1, 0, 64); stA(1, 0, 64); stB(1, 1, 64);                                               \
    asm volatile("s_waitcnt vmcnt(6)" ::: "memory");                                           \
    __builtin_amdgcn_s_barrier();                                                              \
    const int nIter = nk >> 1;                                                                 \
    for (int it = 0; it < nIter; ++it) {                                                       \
        const int t_ = 2 * it, u_ = t_ + 1;                                                    \
        const int ku = u_ * 64;                                                                \
        const int kv = ((t_ + 2 < nk) ? t_ + 2 : t_) * 64;                                     \
        const int kw = ((u_ + 2 < nk) ? u_ + 2 : u_) * 64;                                     \
        ldB(0, 0, b0); ldA(0, 0, aF, aH);                                                      \
        stA(1, 1, ku);                                                                         \
        asm volatile("s_waitcnt lgkmcnt(8)" ::: "memory");                                     \
        __builtin_amdgcn_s_barrier();                                                          \
        asm volatile("s_waitcnt lgkmcnt(0)" ::: "memory");                                     \
        __builtin_amdgcn_s_setprio(1); MFMA16(aF, b0, 0); __builtin_amdgcn_s_setprio(0);       \
        __builtin_amdgcn_s_barrier();                                                          \
        ldB(0, 1, b1);                                                                         \
        stB(0, 0, kv);                                                                         \
        __builtin_amdgcn_s_barrier();                                                          \
        asm volatile("s_waitcnt lgkmcnt(0)" ::: "memory");                                     \
        __builtin_amdgcn_s_setprio(1); MFMA16(aH, b1, 0); __builtin_amdgcn_s_setprio(0);       \
        __builtin_amdgcn_s_barrier();                                                          \
        ldA(0, 1, aF, aH);                                                                     \
        stA(0, 0, kv);                                                                         \
        __builtin_amdgcn_s_barrier();                                                          \
        asm volatile("s_waitcnt lgkmcnt(0)" ::: "memory");                                     \
        __builtin_amdgcn_s_setprio(1); MFMA16(aH, b1, 4); __builtin_amdgcn_s_setprio(0);       \
        __builtin_amdgcn_s_barrier();                                                          \
        stB(0, 1, kv);                                                                         \
        __builtin_amdgcn_s_barrier();                                                          \
        __builtin_amdgcn_s_setprio(1); MFMA16(aF, b0, 4); __builtin_amdgcn_s_setprio(0);       \
        asm volatile("s_waitcnt vmcnt(6)" ::: "memory");                                       \
        __builtin_amdgcn_s_barrier();                                                          \
        ldB(1, 0, b0); ldA(1, 0, aF, aH);                                                      \
        stA(0, 1, kv);                                                                         \
        asm volatile("s_waitcnt lgkmcnt(8)" ::: "memory");                                     \
        __builtin_amdgcn_s_barrier();                                                          \
        asm volatile("s_waitcnt lgkmcnt(0)" ::: "memory");                                     \
        __builtin_amdgcn_s_setprio(1); MFMA16(aF, b0, 0); __builtin_amdgcn_s_setprio(0);       \
        __builtin_amdgcn_s_barrier();                                                          \
        ldB(1, 1, b1);                                                                         \
        stB(1, 0, kw);                                                                         \
        __builtin_amdgcn_s_barrier();                                                          \
        asm volatile("s_waitcnt lgkmcnt(0)" ::: "memory");                                     \
        __builtin_amdgcn_s_setprio(1); MFMA16(aH, b1, 0); __builtin_amdgcn_s_setprio(0);       \
        __builtin_amdgcn_s_barrier();                                                          \
        ldA(1, 1, aF, aH);                                                                     \
        stA(1, 0, kw);                                                                         \
        __builtin_amdgcn_s_barrier();                                                          \
        asm volatile("s_waitcnt lgkmcnt(0)" ::: "memory");                                     \
        __builtin_amdgcn_s_setprio(1); MFMA16(aH, b1, 4); __builtin_amdgcn_s_setprio(0);       \
        __builtin_amdgcn_s_barrier();                                                          \
        stB(1, 1, kw);                                                                         \
        __builtin_amdgcn_s_barrier();                                                          \
        __builtin_amdgcn_s_setprio(1); MFMA16(aF, b0, 4); __builtin_amdgcn_s_setprio(0);       \
        asm volatile("s_waitcnt vmcnt(6)" ::: "memory");                                       \
        __builtin_amdgcn_s_barrier();                                                          \
    }                                                                                          \
    asm volatile("s_waitcnt vmcnt(0)" ::: "memory");                                           \
    __syncthreads();

#define MFMA16(aa, bb, base)                                                                   \
    _Pragma("unroll") for (int m_ = 0; m_ < 4; m_++)                                           \
        _Pragma("unroll") for (int n_ = 0; n_ < 4; n_++)                                       \
            acc[(base) + m_][n_] = __builtin_amdgcn_mfma_f32_16x16x32_bf16(                    \
                (aa)[m_], (bb)[n_], acc[(base) + m_][n_], 0, 0, 0);

// ================= GEMM 256x256 template (FFN): EPI 2 = relu+bf16; 3 = split-K partial ====
template <int EPI>
__global__ __launch_bounds__(512, 2) void gemm256(const unsigned short* __restrict__ A,
                                                  const unsigned short* __restrict__ Bt,
                                                  const float* __restrict__ bias,
                                                  unsigned short* __restrict__ outB,
                                                  int N, int lda, int ldb, int nk, P8 po) {
    __shared__ unsigned short SM[2][2][2][8192];
    const int tid = threadIdx.x;
    const int lane = tid & 63, wid = tid >> 6;
    const int l4 = lane & 15, g = lane >> 4;
    const int wr = wid >> 2, wc = wid & 3;
    BlkMap bm = remap_block();
    const int m0 = bm.m * 256, n0 = bm.n * 256, z = bm.z;
    A += (size_t)z * (nk * 64);
    Bt += (size_t)z * (nk * 64);
    const int sw = l4 & 7;

    const int fl0 = tid, fl1 = 512 + tid;
    const int lr0 = fl0 >> 3, ch0 = (fl0 & 7) ^ (lr0 & 7);
    const int lr1 = fl1 >> 3, ch1 = (fl1 & 7) ^ (lr1 & 7);
    const size_t A64 = (size_t)64 * lda;
    const unsigned short* pA0 = A + (size_t)(m0 + (lr0 >> 6) * 128 + (lr0 & 63)) * lda + ch0 * 8;
    const unsigned short* pA1 = A + (size_t)(m0 + (lr1 >> 6) * 128 + (lr1 & 63)) * lda + ch1 * 8;
    const unsigned short* pB0 = Bt + (size_t)(n0 + (ch0 >> 2) * 128 + lr0) * ldb + (ch0 & 3) * 8;
    const unsigned short* pB1 = Bt + (size_t)(n0 + (ch1 >> 2) * 128 + lr1) * ldb + (ch1 & 3) * 8;

    auto stA = [&](int d, int mh, int kofs) {
        char* base = (char*)&SM[0][d][mh][0];
        gload_lds16(pA0 + (size_t)mh * A64 + kofs, base + fl0 * 16);
        gload_lds16(pA1 + (size_t)mh * A64 + kofs, base + fl1 * 16);
    };
    auto stB = [&](int d, int ks, int kofs) {
        char* base = (char*)&SM[1][d][ks][0];
        gload_lds16(pB0 + ks * 32 + kofs, base + fl0 * 16);
        gload_lds16(pB1 + ks * 32 + kofs, base + fl1 * 16);
    };

    f32x4 acc[8][4] = {};
    short8 aF[4], aH[4], b0[4], b1[4];

    auto ldA = [&](int d, int mh, short8* d0, short8* d1) {
#pragma unroll
        for (int m = 0; m < 4; m++) {
            const char* rp = (const char*)&SM[0][d][mh][0] + (wr * 64 + m * 16 + l4) * 128;
            d0[m] = *(const short8*)(rp + ((g ^ sw) * 16));
            d1[m] = *(const short8*)(rp + (((4 + g) ^ sw) * 16));
        }
    };
    auto ldB = [&](int d, int ks, short8* dst) {
#pragma unroll
        for (int n = 0; n < 4; n++) {
            const char* rp = (const char*)&SM[1][d][ks][0] + ((wc & 1) * 64 + n * 16 + l4) * 128;
            dst[n] = *(const short8*)(rp + ((((wc >> 1) * 4 + g) ^ sw) * 16));
        }
    };

    G256_BODY()

    unsigned short* eb = (unsigned short*)SM;
    unsigned short* oB = (EPI == 3) ? po.o[z] : outB;
    const int colL = wc * 64 + l4;
#pragma unroll
    for (int h = 0; h < 2; ++h) {
        if (wr == h) {
#pragma unroll
            for (int mm = 0; mm < 8; mm++) {
                const int base_r = (mm < 4 ? mm * 16 : 64 + (mm - 4) * 16) + g * 4;
#pragma unroll
                for (int n = 0; n < 4; n++) {
                    float bv = (EPI == 3 && z != 0) ? 0.f : bias[n0 + colL + n * 16];
#pragma unroll
                    for (int r = 0; r < 4; r++) {
                        float v = acc[mm][n][r] + bv;
                        if (EPI == 2) v = fmaxf(v, 0.f);
                        eb[(base_r + r) * 260 + colL + n * 16] = f2bf(v);
                    }
                }
            }
        }
        __syncthreads();
        const int gr0 = m0 + h * 128;
#pragma unroll
        for (int j = 0; j < 8; j++) {
            const int f = j * 8192 + tid * 16;
            const int row = f >> 9;
            const int colb = f & 511;
            short8 v = *(const short8*)((const char*)eb + row * 520 + colb);
            *(short8*)(oB + (size_t)(gr0 + row) * N + n0 + (colb >> 1)) = v;
        }
        if (h == 0) __syncthreads();
    }
}

// ================= fused multi-job GEMM (QKV + eKV), 8-phase, runtime epilogue ==========
struct GJob {
    const unsigned short *A, *Bt;
    const float* bias;
    unsigned short *out, *vt;
    int N, lda, ldb, nk, vthresh, nwg, gx;
};
struct GJ2 { GJob j[2]; };
__global__ __launch_bounds__(512, 2) void gemm256j(GJ2 p) {
    __shared__ unsigned short SM[2][2][2][8192];
    const int tid = threadIdx.x;
    const int lane = tid & 63, wid = tid >> 6;
    const int l4 = lane & 15, g = lane >> 4;
    const int wr = wid >> 2, wc = wid & 3;

    int f = blockIdx.x;
    const int ji = (f < p.j[0].nwg) ? 0 : 1;
    if (ji) f -= p.j[0].nwg;
    const GJob jb = p.j[ji];
    const int id = (f & 7) * (jb.nwg >> 3) + (f >> 3);
    const int gwsh = (jb.gx & 7) ? 2 : 3;
    const int gw = 1 << gwsh;
    const int gy = jb.nwg / jb.gx;
    const int gsz = gw * gy;
    const int grp = id / gsz;
    const int rem = id - grp * gsz;
    const int m0 = (rem >> gwsh) * 256;
    const int n0 = ((grp << gwsh) + (rem & (gw - 1))) * 256;

    const unsigned short* A = jb.A;
    const unsigned short* Bt = jb.Bt;
    const int lda = jb.lda, ldb = jb.ldb, nk = jb.nk;
    const int sw = l4 & 7;

    const int fl0 = tid, fl1 = 512 + tid;
    const int lr0 = fl0 >> 3, ch0 = (fl0 & 7) ^ (lr0 & 7);
    const int lr1 = fl1 >> 3, ch1 = (fl1 & 7) ^ (lr1 & 7);
    const size_t A64 = (size_t)64 * lda;
    const unsigned short* pA0 = A + (size_t)(m0 + (lr0 >> 6) * 128 + (lr0 & 63)) * lda + ch0 * 8;
    const unsigned short* pA1 = A + (size_t)(m0 + (lr1 >> 6) * 128 + (lr1 & 63)) * lda + ch1 * 8;
    const unsigned short* pB0 = Bt + (size_t)(n0 + (ch0 >> 2) * 128 + lr0) * ldb + (ch0 & 3) * 8;
    const unsigned short* pB1 = Bt + (size_t)(n0 + (ch1 >> 2) * 128 + lr1) * ldb + (ch1 & 3) * 8;

    auto stA = [&](int d, int mh, int kofs) {
        char* base = (char*)&SM[0][d][mh][0];
        gload_lds16(pA0 + (size_t)mh * A64 + kofs, base + fl0 * 16);
        gload_lds16(pA1 + (size_t)mh * A64 + kofs, base + fl1 * 16);
    };
    auto stB = [&](int d, int ks, int kofs) {
        char* base = (char*)&SM[1][d][ks][0];
        gload_lds16(pB0 + ks * 32 + kofs, base + fl0 * 16);
        gload_lds16(pB1 + ks * 32 + kofs, base + fl1 * 16);
    };

    f32x4 acc[8][4] = {};
    short8 aF[4], aH[4], b0[4], b1[4];

    auto ldA = [&](int d, int mh, short8* d0, short8* d1) {
#pragma unroll
        for (int m = 0; m < 4; m++) {
            const char* rp = (const char*)&SM[0][d][mh][0] + (wr * 64 + m * 16 + l4) * 128;
            d0[m] = *(const short8*)(rp + ((g ^ sw) * 16));
            d1[m] = *(const short8*)(rp + (((4 + g) ^ sw) * 16));
        }
    };
    auto ldB = [&](int d, int ks, short8* dst) {
#pragma unroll
        for (int n = 0; n < 4; n++) {
            const char* rp = (const char*)&SM[1][d][ks][0] + ((wc & 1) * 64 + n * 16 + l4) * 128;
            dst[n] = *(const short8*)(rp + ((((wc >> 1) * 4 + g) ^ sw) * 16));
        }
    };

    G256_BODY()

    unsigned short* eb = (unsigned short*)SM;
    const int colL = wc * 64 + l4;
#pragma unroll
    for (int h = 0; h < 2; ++h) {
        if (wr == h) {
#pragma unroll
            for (int mm = 0; mm < 8; mm++) {
                const int base_r = (mm < 4 ? mm * 16 : 64 + (mm - 4) * 16) + g * 4;
#pragma unroll
                for (int n = 0; n < 4; n++) {
                    float bv = jb.bias[n0 + colL + n * 16];
#pragma unroll
                    for (int r = 0; r < 4; r++)
                        eb[(base_r + r) * 260 + colL + n * 16] = f2bf(acc[mm][n][r] + bv);
                }
            }
        }
        __syncthreads();
        const int gr0 = m0 + h * 128;
        if (n0 >= jb.vthresh) {
            const int b_ = gr0 >> 10, sb = gr0 & 1023;
#pragma unroll
            for (int j = 0; j < 4; j++) {
                const int id2 = j * 512 + tid;
                const int col = id2 & 255, rseg = id2 >> 8;
                const int rel = n0 - jb.vthresh + col;
                const int hh = rel >> 6, dh = rel & 63;
                short8 v0, v1;
#pragma unroll
                for (int e = 0; e < 8; e++) {
                    v0[e] = eb[(rseg * 16 + e) * 260 + col];
                    v1[e] = eb[(rseg * 16 + 8 + e) * 260 + col];
                }
                unsigned short* dp = jb.vt +
                    ((size_t)(b_ * 16 + hh) * 64 + dh) * 1024 + sb + rseg * 16;
                *(short8*)dp = v0;
                *(short8*)(dp + 8) = v1;
            }
        } else {
#pragma unroll
            for (int j = 0; j < 8; j++) {
                const int ff = j * 8192 + tid * 16;
                const int row = ff >> 9;
                const int colb = ff & 511;
                short8 v = *(const short8*)((const char*)eb + row * 520 + colb);
                *(short8*)(jb.out + (size_t)(gr0 + row) * jb.N + n0 + (colb >> 1)) = v;
            }
        }
        if (h == 0) __syncthreads();
    }
}

// ---------------- GEMM 64x128: 3-buffer depth-2, counted vmcnt, XCD-swizzled ----------------
template <int EPI>
__global__ __launch_bounds__(256) void gemm64_db(const unsigned short* __restrict__ A,
                                                 const unsigned short* __restrict__ Bt,
                                                 const float* __restrict__ bias,
                                                 float* __restrict__ outF,
                                                 unsigned short* __restrict__ outB,
                                                 int M, int N, int Kloop, int lda, int ldb) {
    __shared__ unsigned short As[3][64 * 32];
    __shared__ unsigned short Bs[3][128 * 32];
    const int tid = threadIdx.x;
    const int w = tid >> 6, lane = tid & 63, l4 = lane & 15, g = lane >> 4;
    BlkMap bm = remap_block();
    const int m0 = bm.m * 64, n0 = bm.n * 128;
    f32x4 acc[4][2] = {};
    const int r0 = tid >> 2;
    const int kk = ((tid & 3) ^ ((tid >> 3) & 3)) * 8;
    const int sk = (l4 >> 1) & 3;
    const unsigned short* Ar0 = A + (size_t)(m0 + r0) * lda + kk;
    const unsigned short* Br0 = Bt + (size_t)(n0 + r0) * ldb + kk;
    const unsigned short* Br1 = Bt + (size_t)(n0 + 64 + r0) * ldb + kk;
    auto stage = [&](int sb, int k0) {
        gload_lds16(Ar0 + k0, (char*)As[sb] + tid * 16);
        gload_lds16(Br0 + k0, (char*)Bs[sb] + tid * 16);
        gload_lds16(Br1 + k0, (char*)Bs[sb] + 4096 + tid * 16);
    };
    const int nk = Kloop >> 5;
    stage(0, 0);
    stage(1, 32);
    asm volatile("s_waitcnt vmcnt(3)" ::: "memory");
    __builtin_amdgcn_s_barrier();
    asm volatile("" ::: "memory");
    int buf = 0;
    for (int t = 0; t < nk; ++t) {
        if (t + 2 < nk) {
            int b2 = buf + 2; if (b2 >= 3) b2 -= 3;
            stage(b2, (t + 2) * 32);
        }
        short8 a[4], b[2];
#pragma unroll
        for (int m = 0; m < 4; m++)
            a[m] = *(const short8*)(As[buf] + (m * 16 + l4) * 32 + (g ^ sk) * 8);
#pragma unroll
        for (int n = 0; n < 2; n++)
            b[n] = *(const short8*)(Bs[buf] + (w * 32 + n * 16 + l4) * 32 + (g ^ sk) * 8);
#pragma unroll
        for (int m = 0; m < 4; m++)
#pragma unroll
            for (int n = 0; n < 2; n++)
                acc[m][n] = __builtin_amdgcn_mfma_f32_16x16x32_bf16(a[m], b[n], acc[m][n], 0, 0, 0);
        if (t + 1 < nk) {
            if (t + 2 < nk) asm volatile("s_waitcnt vmcnt(3)" ::: "memory");
            else            asm volatile("s_waitcnt vmcnt(0)" ::: "memory");
            __builtin_amdgcn_s_barrier();
            asm volatile("" ::: "memory");
        }
        buf = (buf + 1 == 3) ? 0 : buf + 1;
    }
    const int rowB = m0 + g * 4;
    const int colB = n0 + w * 32 + l4;
#pragma unroll
    for (int n = 0; n < 2; n++) {
        float bv = bias[colB + n * 16];
#pragma unroll
        for (int m = 0; m < 4; m++) {
#pragma unroll
            for (int r = 0; r < 4; r++) {
                float v = acc[m][n][r] + bv;
                if (EPI == 2) v = fmaxf(v, 0.f);
                size_t idx = (size_t)(rowB + m * 16 + r) * N + colB + n * 16;
                if (EPI == 1) outF[idx] = v;
                else outB[idx] = f2bf(v);
            }
        }
    }
}

// ---------------- flash attention v6: 8 waves / 128 q-rows per block ----------------
template <int CAUSAL>
__global__ __launch_bounds__(512) void attn6_kernel(const unsigned short* __restrict__ Q, int ldq,
                                                    const unsigned short* __restrict__ Kg, int ldk,
                                                    const unsigned short* __restrict__ Vt,
                                                    unsigned short* __restrict__ O) {
    __shared__ unsigned short Kl[2 * 64 * 64];
    __shared__ unsigned short Vl[2 * 64 * 64];
    __shared__ unsigned short Pl[8][16 * 72];
    const int bh = blockIdx.x;
    const int qb = CAUSAL ? (gridDim.y - 1 - blockIdx.y) : blockIdx.y;
    const int b = bh >> 4, h = bh & 15;
    const int tid = threadIdx.x, w = tid >> 6, lane = tid & 63;
    const int l4 = lane & 15, g = lane >> 4;
    const int q0 = qb * 128 + w * 16;
    const unsigned short* Qp = Q + (size_t)(b * Tc + q0 + l4) * ldq + h * DHc + g * 8;
    short8 qf0 = *(const short8*)Qp;
    short8 qf1 = *(const short8*)(Qp + 32);
    const unsigned short* Kbase = Kg + (size_t)(b * 1024) * ldk + h * DHc;
    const unsigned short* Vbase = Vt + (size_t)bh * DHc * 1024;
    f32x4 o[4] = {};
    float mrun = -1e30f, lrun = 0.f;
    const int nT = CAUSAL ? 2 * qb + 2 : 16;
    unsigned short* pw = &Pl[w][l4 * 72];
    const int qi = q0 + l4;

    short8 ones;
#pragma unroll
    for (int j = 0; j < 8; j++) ones[j] = (short)0x3F80;

    const int sr = tid >> 3;
    const int sc_ = (tid & 7) ^ (sr & 7);

    auto stage = [&](int s0, int buf) {
        char* kd = (char*)Kl + buf * 8192;
        char* vd = (char*)Vl + buf * 8192;
        gload_lds16(Kbase + (size_t)(s0 + sr) * ldk + sc_ * 8, kd + tid * 16);
        gload_lds16(Vbase + (size_t)sr * 1024 + s0 + sc_ * 8, vd + tid * 16);
    };

    stage(0, 0);
    __syncthreads();
    int buf = 0;
    const int sw = l4 & 7;

    for (int t = 0; t < nT; ++t) {
        const int s0 = t * 64;
        if (t + 1 < nT) stage(s0 + 64, buf ^ 1);
        if (!CAUSAL || s0 <= q0 + 15) {
            const unsigned short* Kb_ = Kl + buf * 4096;
            const unsigned short* Vb_ = Vl + buf * 4096;
            f32x4 st[4];
            f32x4 z = {0.f, 0.f, 0.f, 0.f};
            __builtin_amdgcn_s_setprio(1);
#pragma unroll
            for (int c = 0; c < 4; c++) {
                const unsigned short* kr = Kb_ + (c * 16 + l4) * 64;
                short8 ka0 = *(const short8*)(kr + ((g ^ sw) * 8));
                short8 ka1 = *(const short8*)(kr + (((g + 4) ^ sw) * 8));
                st[c] = __builtin_amdgcn_mfma_f32_16x16x32_bf16(ka0, qf0, z, 0, 0, 0);
                st[c] = __builtin_amdgcn_mfma_f32_16x16x32_bf16(ka1, qf1, st[c], 0, 0, 0);
            }
            __builtin_amdgcn_s_setprio(0);
            float p[16];
            const bool domask = CAUSAL && (s0 + 63 > q0);
#pragma unroll
            for (int c = 0; c < 4; c++)
#pragma unroll
                for (int r = 0; r < 4; r++) {
                    float v = st[c][r];
                    if (domask && (s0 + c * 16 + g * 4 + r) > qi) v = -1e9f;
                    p[c * 4 + r] = v;
                }
            float m1 = fmaxf(fmaxf(p[0], p[1]), p[2]);
            float m2 = fmaxf(fmaxf(p[3], p[4]), p[5]);
            float m3 = fmaxf(fmaxf(p[6], p[7]), p[8]);
            float m4 = fmaxf(fmaxf(p[9], p[10]), p[11]);
            float m5 = fmaxf(fmaxf(p[12], p[13]), p[14]);
            float tmax = fmaxf(fmaxf(fmaxf(m1, m2), fmaxf(m3, m4)), fmaxf(m5, p[15]));
            tmax = fmaxf(tmax, __shfl_xor(tmax, 16));
            tmax = fmaxf(tmax, __shfl_xor(tmax, 32));
            if (!__all(tmax <= mrun + 11.5f)) {
                float mnew = fmaxf(mrun, tmax);
                float al = fexp2(mrun - mnew);
                lrun *= al;
#pragma unroll
                for (int d = 0; d < 4; d++) o[d] *= al;
                mrun = mnew;
            }
#pragma unroll
            for (int i = 0; i < 16; i++) p[i] = fexp2(p[i] - mrun);
#pragma unroll
            for (int c = 0; c < 4; c++) {
                uint2 u;
                u.x = cvtpk(p[c * 4 + 0], p[c * 4 + 1]);
                u.y = cvtpk(p[c * 4 + 2], p[c * 4 + 3]);
                *(uint2*)(pw + c * 16 + g * 4) = u;
            }
            short8 pb_lo = *(const short8*)(pw + g * 8);
            short8 pb_hi = *(const short8*)(pw + 32 + g * 8);
            __builtin_amdgcn_s_setprio(1);
            f32x4 s4 = __builtin_amdgcn_mfma_f32_16x16x32_bf16(ones, pb_lo, z, 0, 0, 0);
            s4 = __builtin_amdgcn_mfma_f32_16x16x32_bf16(ones, pb_hi, s4, 0, 0, 0);
#pragma unroll
            for (int d = 0; d < 4; d++) {
                const unsigned short* vr = Vb_ + (d * 16 + l4) * 64;
                short8 va0 = *(const short8*)(vr + ((g ^ sw) * 8));
                short8 va1 = *(const short8*)(vr + (((g + 4) ^ sw) * 8));
                o[d] = __builtin_amdgcn_mfma_f32_16x16x32_bf16(va0, pb_lo, o[d], 0, 0, 0);
                o[d] = __builtin_amdgcn_mfma_f32_16x16x32_bf16(va1, pb_hi, o[d], 0, 0, 0);
            }
            __builtin_amdgcn_s_setprio(0);
            lrun += s4[0];
        }
        __syncthreads();
        buf ^= 1;
    }
    float inv = 1.f / lrun;
    unsigned short* Ob = O + (size_t)(b * Tc + q0 + l4) * Dc + h * DHc;
#pragma unroll
    for (int d = 0; d < 4; d++) {
#pragma unroll
        for (int r = 0; r < 4; r++) Ob[d * 16 + g * 4 + r] = f2bf(o[d][r] * inv);
    }
}

// ---------------- fused residual-add + LayerNorm (bf16 a + bf16 res) ----------------
__global__ __launch_bounds__(256) void ln_bf(const unsigned short* __restrict__ a,
                                             const unsigned short* __restrict__ res,
                                             const float* __restrict__ gam,
                                             const float* __restrict__ bet,
                                             unsigned short* __restrict__ outB,
                                             float* __restrict__ outF) {
    int row = blockIdx.x, t = threadIdx.x;
    size_t base = (size_t)row * Dc + t * 4;
    short4v av = *(const short4v*)(a + base);
    short4v rv = *(const short4v*)(res + base);
    float x0 = bf2f((unsigned short)av[0]) + bf2f((unsigned short)rv[0]);
    float x1 = bf2f((unsigned short)av[1]) + bf2f((unsigned short)rv[1]);
    float x2 = bf2f((unsigned short)av[2]) + bf2f((unsigned short)rv[2]);
    float x3 = bf2f((unsigned short)av[3]) + bf2f((unsigned short)rv[3]);
    float s = x0 + x1 + x2 + x3;
    float ss = x0 * x0 + x1 * x1 + x2 * x2 + x3 * x3;
    for (int o = 1; o < 64; o <<= 1) { s += __shfl_xor(s, o); ss += __shfl_xor(ss, o); }
    __shared__ float S1[4], S2[4];
    int w = t >> 6;
    if ((t & 63) == 0) { S1[w] = s; S2[w] = ss; }
    __syncthreads();
    s = S1[0] + S1[1] + S1[2] + S1[3];
    ss = S2[0] + S2[1] + S2[2] + S2[3];
    float mean = s * (1.f / Dc);
    float var = ss * (1.f / Dc) - mean * mean;
    float rstd = rsqrtf(var + 1e-5f);
    int c = t * 4;
    float4 g4 = *(const float4*)(gam + c);
    float4 b4 = *(const float4*)(bet + c);
    float y0 = (x0 - mean) * rstd * g4.x + b4.x;
    float y1 = (x1 - mean) * rstd * g4.y + b4.y;
    float y2 = (x2 - mean) * rstd * g4.z + b4.z;
    float y3 = (x3 - mean) * rstd * g4.w + b4.w;
    if (outB) {
        short4v ob;
        ob[0] = f2bf(y0); ob[1] = f2bf(y1); ob[2] = f2bf(y2); ob[3] = f2bf(y3);
        *(short4v*)(outB + base) = ob;
    }
    if (outF) { float4 ov = {y0, y1, y2, y3}; *(float4*)(outF + base) = ov; }
}

// ---------------- LN over 4 bf16 split-K partials + bf16 residual -> f32 out ----------------
__global__ __launch_bounds__(256) void ln_4b(const unsigned short* __restrict__ p,
                                             const unsigned short* __restrict__ res,
                                             const float* __restrict__ gam,
                                             const float* __restrict__ bet,
                                             float* __restrict__ outF) {
    const size_t PS = (size_t)4096 * 1024;
    int row = blockIdx.x, t = threadIdx.x;
    size_t base = (size_t)row * Dc + t * 4;
    float x0, x1, x2, x3;
    {
        short4v rv = *(const short4v*)(res + base);
        x0 = bf2f((unsigned short)rv[0]); x1 = bf2f((unsigned short)rv[1]);
        x2 = bf2f((unsigned short)rv[2]); x3 = bf2f((unsigned short)rv[3]);
    }
#pragma unroll
    for (int j = 0; j < 4; j++) {
        short4v v = *(const short4v*)(p + j * PS + base);
        x0 += bf2f((unsigned short)v[0]); x1 += bf2f((unsigned short)v[1]);
        x2 += bf2f((unsigned short)v[2]); x3 += bf2f((unsigned short)v[3]);
    }
    float s = x0 + x1 + x2 + x3;
    float ss = x0 * x0 + x1 * x1 + x2 * x2 + x3 * x3;
    for (int o = 1; o < 64; o <<= 1) { s += __shfl_xor(s, o); ss += __shfl_xor(ss, o); }
    __shared__ float S1[4], S2[4];
    int w = t >> 6;
    if ((t & 63) == 0) { S1[w] = s; S2[w] = ss; }
    __syncthreads();
    s = S1[0] + S1[1] + S1[2] + S1[3];
    ss = S2[0] + S2[1] + S2[2] + S2[3];
    float mean = s * (1.f / Dc);
    float var = ss * (1.f / Dc) - mean * mean;
    float rstd = rsqrtf(var + 1e-5f);
    int c = t * 4;
    float4 g4 = *(const float4*)(gam + c);
    float4 b4 = *(const float4*)(bet + c);
    float4 ov;
    ov.x = (x0 - mean) * rstd * g4.x + b4.x;
    ov.y = (x1 - mean) * rstd * g4.y + b4.y;
    ov.z = (x2 - mean) * rstd * g4.z + b4.z;
    ov.w = (x3 - mean) * rstd * g4.w + b4.w;
    *(float4*)(outF + base) = ov;
}

// ---------------- launch ----------------
extern "C" void kernel_launch(void* const* d_in, const int* in_sizes, int n_in,
                              void* d_out, int out_size, void* d_ws, size_t ws_size,
                              hipStream_t stream) {
    const float* x   = (const float*)d_in[0];
    const float* enc = (const float*)d_in[1];
    const float* dWq = (const float*)d_in[4];  const float* dbq = (const float*)d_in[5];
    const float* dWk = (const float*)d_in[6];  const float* dbk = (const float*)d_in[7];
    const float* dWv = (const float*)d_in[8];  const float* dbv = (const float*)d_in[9];
    const float* dWo = (const float*)d_in[10]; const float* dbo = (const float*)d_in[11];
    const float* eWq = (const float*)d_in[12]; const float* ebq = (const float*)d_in[13];
    const float* eWk = (const float*)d_in[14]; const float* ebk = (const float*)d_in[15];
    const float* eWv = (const float*)d_in[16]; const float* ebv = (const float*)d_in[17];
    const float* eWo = (const float*)d_in[18]; const float* ebo = (const float*)d_in[19];
    const float* fW1 = (const float*)d_in[20]; const float* fb1 = (const float*)d_in[21];
    const float* fW2 = (const float*)d_in[22]; const float* fb2 = (const float*)d_in[23];
    const float* g1 = (const float*)d_in[24];  const float* be1 = (const float*)d_in[25];
    const float* g2 = (const float*)d_in[26];  const float* be2 = (const float*)d_in[27];
    const float* g3 = (const float*)d_in[28];  const float* be3 = (const float*)d_in[29];

    const float SC = 0.125f * 1.44269504f;

    char* ws = (char*)d_ws;
    size_t off = 0;
    auto alloc = [&](size_t bytes) -> void* {
        void* p = ws + off;
        off += (bytes + 255) & ~(size_t)255;
        return p;
    };
    const size_t A = (size_t)4096 * 1024;
    const size_t MB1 = (size_t)1024 * 1024;
    char* R1 = (char*)alloc(32 * 1024 * 1024);
    unsigned short* qkv = (unsigned short*)R1;                       // stride 3072 (Q,K cols only)
    unsigned short* qx  = (unsigned short*)(R1 + 16 * 1024 * 1024);  // stride 1024
    unsigned short* h1  = (unsigned short*)R1;                       // 4096x4096
    unsigned short* xb   = (unsigned short*)alloc(A * 2);
    unsigned short* encb = (unsigned short*)alloc(A * 2);
    unsigned short* wqkv = (unsigned short*)alloc(3 * MB1 * 2);
    unsigned short* wekv = (unsigned short*)alloc(2 * MB1 * 2);
    unsigned short* weq  = (unsigned short*)alloc(MB1 * 2);
    unsigned short* wdo  = (unsigned short*)alloc(MB1 * 2);
    unsigned short* weo  = (unsigned short*)alloc(MB1 * 2);
    unsigned short* wf1  = (unsigned short*)alloc(4 * MB1 * 2);
    unsigned short* wf2  = (unsigned short*)alloc(4 * MB1 * 2);
    float* bqkv = (float*)alloc(3072 * 4);
    float* bekv = (float*)alloc(2048 * 4);
    float* ebq_s = (float*)alloc(1024 * 4);
    unsigned short* VtB = (unsigned short*)alloc(A * 2);
    unsigned short* ab  = (unsigned short*)alloc(A * 2);
    unsigned short* tmpB = (unsigned short*)alloc(A * 2);
    unsigned short* dB = (unsigned short*)alloc(A * 2);
    unsigned short* fB = (unsigned short*)alloc(A * 2);
    unsigned short* kb  = (unsigned short*)alloc(A * 2);   // cross-K rows (stride 1024)
    unsigned short* vtc = (unsigned short*)alloc(A * 2);   // cross V^T
    unsigned short* pfb = VtB;                             // FFN2 partials alias VtB..dB
    (void)ws_size; (void)in_sizes; (void)n_in; (void)out_size;

    cast2_f32_bf16<<<dim3(2048, 2), 256, 0, stream>>>(x, enc, xb, encb, (int)(A / 8));

    TJ16 tj;
    tj.j[0] = {dWq, wqkv,           1024, 1024, SC};
    tj.j[1] = {dWk, wqkv + MB1,     1024, 1024, 1.f};
    tj.j[2] = {dWv, wqkv + 2 * MB1, 1024, 1024, 1.f};
    tj.j[3] = {eWk, wekv,           1024, 1024, 1.f};
    tj.j[4] = {eWv, wekv + MB1,     1024, 1024, 1.f};
    tj.j[5] = {eWq, weq,            1024, 1024, SC};
    tj.j[6] = {dWo, wdo,            1024, 1024, 1.f};
    tj.j[7] = {eWo, weo,            1024, 1024, 1.f};
    for (int jj = 0; jj < 4; jj++) {
        tj.j[8 + jj]  = {fW1 + 1024 * jj, wf1 + (size_t)1024 * jj * 1024, 4096, 1024, 1.f};
        tj.j[12 + jj] = {fW2 + (size_t)1024 * jj * 1024, wf2 + 1024 * jj, 1024, 4096, 1.f};
    }
    transpose_cast16<<<dim3(16, 16, 16), 256, 0, stream>>>(tj);
    prep_bias<<<24, 256, 0, stream>>>(dbq, dbk, dbv, ebk, ebv, ebq, bqkv, bekv, ebq_s, SC);

    P8 z8{};

    // ---- fused QKV + eKV dispatch (320 blocks) ----
    {
        GJ2 gj;
        gj.j[0] = {xb, wqkv, bqkv, qkv, VtB, 3072, 1024, 1024, 16, 2048, 192, 12};
        gj.j[1] = {encb, wekv, bekv, kb, vtc, 1024, 1024, 1024, 16, 1024, 128, 8};
        gemm256j<<<dim3(320), 512, 0, stream>>>(gj);
    }

    // ---- self-attention block ----
    attn6_kernel<1><<<dim3(64, 8), 512, 0, stream>>>(qkv, 3072, qkv + 1024, 3072, VtB, ab);
    gemm64_db<0><<<dim3(8, 64), 256, 0, stream>>>(ab, wdo, dbo, nullptr, tmpB, 4096, 1024, 1024, 1024, 1024);
    ln_bf<<<4096, 256, 0, stream>>>(tmpB, xb, g1, be1, dB, nullptr);

    // ---- cross-attention block ----
    gemm64_db<0><<<dim3(8, 64), 256, 0, stream>>>(dB, weq, ebq_s, nullptr, qx, 4096, 1024, 1024, 1024, 1024);
    attn6_kernel<0><<<dim3(64, 8), 512, 0, stream>>>(qx, 1024, kb, 1024, vtc, ab);
    gemm64_db<0><<<dim3(8, 64), 256, 0, stream>>>(ab, weo, ebo, nullptr, tmpB, 4096, 1024, 1024, 1024, 1024);
    ln_bf<<<4096, 256, 0, stream>>>(tmpB, dB, g2, be2, fB, nullptr);

    // ---- FFN block (reverted to proven 8-phase 256^2 kernels) ----
    gemm256<2><<<dim3(16, 16), 512, 0, stream>>>(fB, wf1, fb1, h1, 4096, 1024, 1024, 16, z8);
    {
        P8 pf{};
        pf.o[0] = pfb;
        pf.o[1] = pfb + A;
        pf.o[2] = pfb + 2 * A;
        pf.o[3] = pfb + 3 * A;
        gemm256<3><<<dim3(4, 16, 4), 512, 0, stream>>>(h1, wf2, fb2, nullptr, 1024, 4096, 4096, 16, pf);
    }
    ln_4b<<<4096, 256, 0, stream>>>(pfb, fB, g3, be3, (float*)d_out);
}

// Round 21
// 313.455 us; speedup vs baseline: 1.0137x; 1.0011x over previous
//
#include <hip/hip_runtime.h>

static constexpr int Bc = 4, Tc = 1024, Sc = 1024, Dc = 1024, Hc = 16, DHc = 64, FFc = 4096;

typedef __attribute__((ext_vector_type(8))) short short8;
typedef __attribute__((ext_vector_type(4))) short short4v;
typedef __attribute__((ext_vector_type(4))) float f32x4;

struct P8 { unsigned short* o[8]; };

__device__ __forceinline__ unsigned short f2bf(float f) {
    unsigned int u = __float_as_uint(f);
    unsigned int r = u + 0x7fffu + ((u >> 16) & 1u);
    return (unsigned short)(r >> 16);
}
__device__ __forceinline__ float bf2f(unsigned short u) {
    return __uint_as_float(((unsigned int)u) << 16);
}
__device__ __forceinline__ float fexp2(float x) {
    float r; asm("v_exp_f32 %0, %1" : "=v"(r) : "v"(x)); return r;
}
__device__ __forceinline__ unsigned int cvtpk(float a, float b) {
    unsigned int r;
    asm("v_cvt_pk_bf16_f32 %0, %1, %2" : "=v"(r) : "v"(a), "v"(b));
    return r;
}

__device__ __forceinline__ void gload_lds16(const void* g, void* l) {
    __builtin_amdgcn_global_load_lds((const __attribute__((address_space(1))) void*)g,
                                     (__attribute__((address_space(3))) void*)l, 16, 0, 0);
}

// ---------------- cast f32 -> bf16 (two tensors in one launch) ----------------
__global__ __launch_bounds__(256) void cast2_f32_bf16(const float* __restrict__ inA,
                                                      const float* __restrict__ inB,
                                                      unsigned short* __restrict__ outA,
                                                      unsigned short* __restrict__ outB, int n8) {
    int i = blockIdx.x * 256 + threadIdx.x;
    if (i >= n8) return;
    const float* in = blockIdx.y ? inB : inA;
    unsigned short* out = blockIdx.y ? outB : outA;
    const float4* p = (const float4*)in + (size_t)i * 2;
    float4 a = p[0], b = p[1];
    short8 o;
    o[0] = f2bf(a.x); o[1] = f2bf(a.y); o[2] = f2bf(a.z); o[3] = f2bf(a.w);
    o[4] = f2bf(b.x); o[5] = f2bf(b.y); o[6] = f2bf(b.z); o[7] = f2bf(b.w);
    *(short8*)(out + (size_t)i * 8) = o;
}

// ---------------- unified weight transpose+cast: 16 jobs of 1024x1024 views ----------------
struct TJ { const float* s; unsigned short* d; int ss, ds; float scl; };
struct TJ16 { TJ j[16]; };
__global__ __launch_bounds__(256) void transpose_cast16(TJ16 p) {
    __shared__ float t[64][65];
    const TJ jb = p.j[blockIdx.z];
    const int c0 = blockIdx.x * 64, r0 = blockIdx.y * 64;
    const int tid = threadIdx.x;
    const int rr = tid >> 2, cc = (tid & 3) * 16;
    const float* src = jb.s + (size_t)(r0 + rr) * jb.ss + c0 + cc;
#pragma unroll
    for (int i = 0; i < 4; i++) {
        float4 v = *(const float4*)(src + i * 4);
        t[rr][cc + i * 4 + 0] = v.x;
        t[rr][cc + i * 4 + 1] = v.y;
        t[rr][cc + i * 4 + 2] = v.z;
        t[rr][cc + i * 4 + 3] = v.w;
    }
    __syncthreads();
#pragma unroll
    for (int half = 0; half < 2; half++) {
        const int id = half * 256 + tid;
        const int a = id >> 3, b0 = id & 7;
        short8 o;
#pragma unroll
        for (int e = 0; e < 8; e++) o[e] = f2bf(t[b0 * 8 + e][a] * jb.scl);
        *(short8*)(jb.d + (size_t)(c0 + a) * jb.ds + r0 + b0 * 8) = o;
    }
}

// ---------------- all bias prep in one launch (6144 elems) ----------------
__global__ void prep_bias(const float* dbq, const float* dbk, const float* dbv,
                          const float* ebk, const float* ebv, const float* ebq,
                          float* __restrict__ bqkv, float* __restrict__ bekv,
                          float* __restrict__ ebq_s, float SC) {
    int i = blockIdx.x * 256 + threadIdx.x;
    int seg = i >> 10, j = i & 1023;
    switch (seg) {
        case 0: bqkv[j] = dbq[j] * SC; break;
        case 1: bqkv[1024 + j] = dbk[j]; break;
        case 2: bqkv[2048 + j] = dbv[j]; break;
        case 3: bekv[j] = ebk[j]; break;
        case 4: bekv[1024 + j] = ebv[j]; break;
        default: ebq_s[j] = ebq[j] * SC; break;
    }
}

// ---- block remap: chunked-XCD + group-major rasterization (bijective, nwg%8==0) ----
struct BlkMap { int m, n, z; };
__device__ __forceinline__ BlkMap remap_block() {
    const int gx = gridDim.x, gy = gridDim.y;
    const int nxy = gx * gy;
    const int nwg = nxy * gridDim.z;
    const int flat = (blockIdx.z * gy + blockIdx.y) * gx + blockIdx.x;
    const int id = (flat & 7) * (nwg >> 3) + (flat >> 3);
    const int pz = id / nxy;
    const int rz = id - pz * nxy;
    const int gwsh = (gx & 7) ? 2 : 3;
    const int gw = 1 << gwsh;
    const int gsz = gw * gy;
    const int grp = rz / gsz;
    const int rem = rz - grp * gsz;
    BlkMap r;
    r.m = rem >> gwsh;
    r.n = (grp << gwsh) + (rem & (gw - 1));
    r.z = pz;
    return r;
}

// shared inner K-loop body (8-phase m201 schedule)
// NOTE: tail "dummy" re-stages (kv/kw clamps) are intentional — they keep the vmcnt
// FIFO count uniform so vmcnt(6) at P3/P7 certifies exactly the needed half-tiles.
#define G256_BODY()                                                                            \
    stB(0, 0, 0); stA(0, 0, 0); stB(0, 1, 0); stA(0, 1, 0);                                    \
    stB(1, 0, 64); stA(1, 0, 64); stB(1, 1, 64);                                               \
    asm volatile("s_waitcnt vmcnt(6)" ::: "memory");                                           \
    __builtin_amdgcn_s_barrier();                                                              \
    const int nIter = nk >> 1;                                                                 \
    for (int it = 0; it < nIter; ++it) {                                                       \
        const int t_ = 2 * it, u_ = t_ + 1;                                                    \
        const int ku = u_ * 64;                                                                \
        const int kv = ((t_ + 2 < nk) ? t_ + 2 : t_) * 64;                                     \
        const int kw = ((u_ + 2 < nk) ? u_ + 2 : u_) * 64;                                     \
        ldB(0, 0, b0); ldA(0, 0, aF, aH);                                                      \
        stA(1, 1, ku);                                                                         \
        asm volatile("s_waitcnt lgkmcnt(8)" ::: "memory");                                     \
        __builtin_amdgcn_s_barrier();                                                          \
        asm volatile("s_waitcnt lgkmcnt(0)" ::: "memory");                                     \
        __builtin_amdgcn_s_setprio(1); MFMA16(aF, b0, 0); __builtin_amdgcn_s_setprio(0);       \
        __builtin_amdgcn_s_barrier();                                                          \
        ldB(0, 1, b1);                                                                         \
        stB(0, 0, kv);                                                                         \
        __builtin_amdgcn_s_barrier();                                                          \
        asm volatile("s_waitcnt lgkmcnt(0)" ::: "memory");                                     \
        __builtin_amdgcn_s_setprio(1); MFMA16(aH, b1, 0); __builtin_amdgcn_s_setprio(0);       \
        __builtin_amdgcn_s_barrier();                                                          \
        ldA(0, 1, aF, aH);                                                                     \
        stA(0, 0, kv);                                                                         \
        __builtin_amdgcn_s_barrier();                                                          \
        asm volatile("s_waitcnt lgkmcnt(0)" ::: "memory");                                     \
        __builtin_amdgcn_s_setprio(1); MFMA16(aH, b1, 4); __builtin_amdgcn_s_setprio(0);       \
        __builtin_amdgcn_s_barrier();                                                          \
        stB(0, 1, kv);                                                                         \
        __builtin_amdgcn_s_barrier();                                                          \
        __builtin_amdgcn_s_setprio(1); MFMA16(aF, b0, 4); __builtin_amdgcn_s_setprio(0);       \
        asm volatile("s_waitcnt vmcnt(6)" ::: "memory");                                       \
        __builtin_amdgcn_s_barrier();                                                          \
        ldB(1, 0, b0); ldA(1, 0, aF, aH);                                                      \
        stA(0, 1, kv);                                                                         \
        asm volatile("s_waitcnt lgkmcnt(8)" ::: "memory");                                     \
        __builtin_amdgcn_s_barrier();                                                          \
        asm volatile("s_waitcnt lgkmcnt(0)" ::: "memory");                                     \
        __builtin_amdgcn_s_setprio(1); MFMA16(aF, b0, 0); __builtin_amdgcn_s_setprio(0);       \
        __builtin_amdgcn_s_barrier();                                                          \
        ldB(1, 1, b1);                                                                         \
        stB(1, 0, kw);                                                                         \
        __builtin_amdgcn_s_barrier();                                                          \
        asm volatile("s_waitcnt lgkmcnt(0)" ::: "memory");                                     \
        __builtin_amdgcn_s_setprio(1); MFMA16(aH, b1, 0); __builtin_amdgcn_s_setprio(0);       \
        __builtin_amdgcn_s_barrier();                                                          \
        ldA(1, 1, aF, aH);                                                                     \
        stA(1, 0, kw);                                                                         \
        __builtin_amdgcn_s_barrier();                                                          \
        asm volatile("s_waitcnt lgkmcnt(0)" ::: "memory");                                     \
        __builtin_amdgcn_s_setprio(1); MFMA16(aH, b1, 4); __builtin_amdgcn_s_setprio(0);       \
        __builtin_amdgcn_s_barrier();                                                          \
        stB(1, 1, kw);                                                                         \
        __builtin_amdgcn_s_barrier();                                                          \
        __builtin_amdgcn_s_setprio(1); MFMA16(aF, b0, 4); __builtin_amdgcn_s_setprio(0);       \
        asm volatile("s_waitcnt vmcnt(6)" ::: "memory");                                       \
        __builtin_amdgcn_s_barrier();                                                          \
    }                                                                                          \
    asm volatile("s_waitcnt vmcnt(0)" ::: "memory");                                           \
    __syncthreads();

#define MFMA16(aa, bb, base)                                                                   \
    _Pragma("unroll") for (int m_ = 0; m_ < 4; m_++)                                           \
        _Pragma("unroll") for (int n_ = 0; n_ < 4; n_++)                                       \
            acc[(base) + m_][n_] = __builtin_amdgcn_mfma_f32_16x16x32_bf16(                    \
                (aa)[m_], (bb)[n_], acc[(base) + m_][n_], 0, 0, 0);

// ================= GEMM 256x256 template (FFN): EPI 2 = relu+bf16; 3 = split-K partial ====
template <int EPI>
__global__ __launch_bounds__(512, 2) void gemm256(const unsigned short* __restrict__ A,
                                                  const unsigned short* __restrict__ Bt,
                                                  const float* __restrict__ bias,
                                                  unsigned short* __restrict__ outB,
                                                  int N, int lda, int ldb, int nk, P8 po) {
    __shared__ unsigned short SM[2][2][2][8192];
    const int tid = threadIdx.x;
    const int lane = tid & 63, wid = tid >> 6;
    const int l4 = lane & 15, g = lane >> 4;
    const int wr = wid >> 2, wc = wid & 3;
    BlkMap bm = remap_block();
    const int m0 = bm.m * 256, n0 = bm.n * 256, z = bm.z;
    A += (size_t)z * (nk * 64);
    Bt += (size_t)z * (nk * 64);
    const int sw = l4 & 7;

    const int fl0 = tid, fl1 = 512 + tid;
    const int lr0 = fl0 >> 3, ch0 = (fl0 & 7) ^ (lr0 & 7);
    const int lr1 = fl1 >> 3, ch1 = (fl1 & 7) ^ (lr1 & 7);
    const size_t A64 = (size_t)64 * lda;
    const unsigned short* pA0 = A + (size_t)(m0 + (lr0 >> 6) * 128 + (lr0 & 63)) * lda + ch0 * 8;
    const unsigned short* pA1 = A + (size_t)(m0 + (lr1 >> 6) * 128 + (lr1 & 63)) * lda + ch1 * 8;
    const unsigned short* pB0 = Bt + (size_t)(n0 + (ch0 >> 2) * 128 + lr0) * ldb + (ch0 & 3) * 8;
    const unsigned short* pB1 = Bt + (size_t)(n0 + (ch1 >> 2) * 128 + lr1) * ldb + (ch1 & 3) * 8;

    auto stA = [&](int d, int mh, int kofs) {
        char* base = (char*)&SM[0][d][mh][0];
        gload_lds16(pA0 + (size_t)mh * A64 + kofs, base + fl0 * 16);
        gload_lds16(pA1 + (size_t)mh * A64 + kofs, base + fl1 * 16);
    };
    auto stB = [&](int d, int ks, int kofs) {
        char* base = (char*)&SM[1][d][ks][0];
        gload_lds16(pB0 + ks * 32 + kofs, base + fl0 * 16);
        gload_lds16(pB1 + ks * 32 + kofs, base + fl1 * 16);
    };

    f32x4 acc[8][4] = {};
    short8 aF[4], aH[4], b0[4], b1[4];

    auto ldA = [&](int d, int mh, short8* d0, short8* d1) {
#pragma unroll
        for (int m = 0; m < 4; m++) {
            const char* rp = (const char*)&SM[0][d][mh][0] + (wr * 64 + m * 16 + l4) * 128;
            d0[m] = *(const short8*)(rp + ((g ^ sw) * 16));
            d1[m] = *(const short8*)(rp + (((4 + g) ^ sw) * 16));
        }
    };
    auto ldB = [&](int d, int ks, short8* dst) {
#pragma unroll
        for (int n = 0; n < 4; n++) {
            const char* rp = (const char*)&SM[1][d][ks][0] + ((wc & 1) * 64 + n * 16 + l4) * 128;
            dst[n] = *(const short8*)(rp + ((((wc >> 1) * 4 + g) ^ sw) * 16));
        }
    };

    G256_BODY()

    unsigned short* eb = (unsigned short*)SM;
    unsigned short* oB = (EPI == 3) ? po.o[z] : outB;
    const int colL = wc * 64 + l4;
#pragma unroll
    for (int h = 0; h < 2; ++h) {
        if (wr == h) {
#pragma unroll
            for (int mm = 0; mm < 8; mm++) {
                const int base_r = (mm < 4 ? mm * 16 : 64 + (mm - 4) * 16) + g * 4;
#pragma unroll
                for (int n = 0; n < 4; n++) {
                    float bv = (EPI == 3 && z != 0) ? 0.f : bias[n0 + colL + n * 16];
#pragma unroll
                    for (int r = 0; r < 4; r++) {
                        float v = acc[mm][n][r] + bv;
                        if (EPI == 2) v = fmaxf(v, 0.f);
                        eb[(base_r + r) * 260 + colL + n * 16] = f2bf(v);
                    }
                }
            }
        }
        __syncthreads();
        const int gr0 = m0 + h * 128;
#pragma unroll
        for (int j = 0; j < 8; j++) {
            const int f = j * 8192 + tid * 16;
            const int row = f >> 9;
            const int colb = f & 511;
            short8 v = *(const short8*)((const char*)eb + row * 520 + colb);
            *(short8*)(oB + (size_t)(gr0 + row) * N + n0 + (colb >> 1)) = v;
        }
        if (h == 0) __syncthreads();
    }
}

// ================= fused multi-job GEMM (QKV + eKV), 8-phase, runtime epilogue ==========
struct GJob {
    const unsigned short *A, *Bt;
    const float* bias;
    unsigned short *out, *vt;
    int N, lda, ldb, nk, vthresh, nwg, gx;
};
struct GJ2 { GJob j[2]; };
__global__ __launch_bounds__(512, 2) void gemm256j(GJ2 p) {
    __shared__ unsigned short SM[2][2][2][8192];
    const int tid = threadIdx.x;
    const int lane = tid & 63, wid = tid >> 6;
    const int l4 = lane & 15, g = lane >> 4;
    const int wr = wid >> 2, wc = wid & 3;

    int f = blockIdx.x;
    const int ji = (f < p.j[0].nwg) ? 0 : 1;
    if (ji) f -= p.j[0].nwg;
    const GJob jb = p.j[ji];
    const int id = (f & 7) * (jb.nwg >> 3) + (f >> 3);
    const int gwsh = (jb.gx & 7) ? 2 : 3;
    const int gw = 1 << gwsh;
    const int gy = jb.nwg / jb.gx;
    const int gsz = gw * gy;
    const int grp = id / gsz;
    const int rem = id - grp * gsz;
    const int m0 = (rem >> gwsh) * 256;
    const int n0 = ((grp << gwsh) + (rem & (gw - 1))) * 256;

    const unsigned short* A = jb.A;
    const unsigned short* Bt = jb.Bt;
    const int lda = jb.lda, ldb = jb.ldb, nk = jb.nk;
    const int sw = l4 & 7;

    const int fl0 = tid, fl1 = 512 + tid;
    const int lr0 = fl0 >> 3, ch0 = (fl0 & 7) ^ (lr0 & 7);
    const int lr1 = fl1 >> 3, ch1 = (fl1 & 7) ^ (lr1 & 7);
    const size_t A64 = (size_t)64 * lda;
    const unsigned short* pA0 = A + (size_t)(m0 + (lr0 >> 6) * 128 + (lr0 & 63)) * lda + ch0 * 8;
    const unsigned short* pA1 = A + (size_t)(m0 + (lr1 >> 6) * 128 + (lr1 & 63)) * lda + ch1 * 8;
    const unsigned short* pB0 = Bt + (size_t)(n0 + (ch0 >> 2) * 128 + lr0) * ldb + (ch0 & 3) * 8;
    const unsigned short* pB1 = Bt + (size_t)(n0 + (ch1 >> 2) * 128 + lr1) * ldb + (ch1 & 3) * 8;

    auto stA = [&](int d, int mh, int kofs) {
        char* base = (char*)&SM[0][d][mh][0];
        gload_lds16(pA0 + (size_t)mh * A64 + kofs, base + fl0 * 16);
        gload_lds16(pA1 + (size_t)mh * A64 + kofs, base + fl1 * 16);
    };
    auto stB = [&](int d, int ks, int kofs) {
        char* base = (char*)&SM[1][d][ks][0];
        gload_lds16(pB0 + ks * 32 + kofs, base + fl0 * 16);
        gload_lds16(pB1 + ks * 32 + kofs, base + fl1 * 16);
    };

    f32x4 acc[8][4] = {};
    short8 aF[4], aH[4], b0[4], b1[4];

    auto ldA = [&](int d, int mh, short8* d0, short8* d1) {
#pragma unroll
        for (int m = 0; m < 4; m++) {
            const char* rp = (const char*)&SM[0][d][mh][0] + (wr * 64 + m * 16 + l4) * 128;
            d0[m] = *(const short8*)(rp + ((g ^ sw) * 16));
            d1[m] = *(const short8*)(rp + (((4 + g) ^ sw) * 16));
        }
    };
    auto ldB = [&](int d, int ks, short8* dst) {
#pragma unroll
        for (int n = 0; n < 4; n++) {
            const char* rp = (const char*)&SM[1][d][ks][0] + ((wc & 1) * 64 + n * 16 + l4) * 128;
            dst[n] = *(const short8*)(rp + ((((wc >> 1) * 4 + g) ^ sw) * 16));
        }
    };

    G256_BODY()

    unsigned short* eb = (unsigned short*)SM;
    const int colL = wc * 64 + l4;
#pragma unroll
    for (int h = 0; h < 2; ++h) {
        if (wr == h) {
#pragma unroll
            for (int mm = 0; mm < 8; mm++) {
                const int base_r = (mm < 4 ? mm * 16 : 64 + (mm - 4) * 16) + g * 4;
#pragma unroll
                for (int n = 0; n < 4; n++) {
                    float bv = jb.bias[n0 + colL + n * 16];
#pragma unroll
                    for (int r = 0; r < 4; r++)
                        eb[(base_r + r) * 260 + colL + n * 16] = f2bf(acc[mm][n][r] + bv);
                }
            }
        }
        __syncthreads();
        const int gr0 = m0 + h * 128;
        if (n0 >= jb.vthresh) {
            const int b_ = gr0 >> 10, sb = gr0 & 1023;
#pragma unroll
            for (int j = 0; j < 4; j++) {
                const int id2 = j * 512 + tid;
                const int col = id2 & 255, rseg = id2 >> 8;
                const int rel = n0 - jb.vthresh + col;
                const int hh = rel >> 6, dh = rel & 63;
                short8 v0, v1;
#pragma unroll
                for (int e = 0; e < 8; e++) {
                    v0[e] = eb[(rseg * 16 + e) * 260 + col];
                    v1[e] = eb[(rseg * 16 + 8 + e) * 260 + col];
                }
                unsigned short* dp = jb.vt +
                    ((size_t)(b_ * 16 + hh) * 64 + dh) * 1024 + sb + rseg * 16;
                *(short8*)dp = v0;
                *(short8*)(dp + 8) = v1;
            }
        } else {
#pragma unroll
            for (int j = 0; j < 8; j++) {
                const int ff = j * 8192 + tid * 16;
                const int row = ff >> 9;
                const int colb = ff & 511;
                short8 v = *(const short8*)((const char*)eb + row * 520 + colb);
                *(short8*)(jb.out + (size_t)(gr0 + row) * jb.N + n0 + (colb >> 1)) = v;
            }
        }
        if (h == 0) __syncthreads();
    }
}

// ---------------- GEMM 64x128: 3-buffer depth-2, counted vmcnt, XCD-swizzled ----------------
template <int EPI>
__global__ __launch_bounds__(256) void gemm64_db(const unsigned short* __restrict__ A,
                                                 const unsigned short* __restrict__ Bt,
                                                 const float* __restrict__ bias,
                                                 float* __restrict__ outF,
                                                 unsigned short* __restrict__ outB,
                                                 int M, int N, int Kloop, int lda, int ldb) {
    __shared__ unsigned short As[3][64 * 32];
    __shared__ unsigned short Bs[3][128 * 32];
    const int tid = threadIdx.x;
    const int w = tid >> 6, lane = tid & 63, l4 = lane & 15, g = lane >> 4;
    BlkMap bm = remap_block();
    const int m0 = bm.m * 64, n0 = bm.n * 128;
    f32x4 acc[4][2] = {};
    const int r0 = tid >> 2;
    const int kk = ((tid & 3) ^ ((tid >> 3) & 3)) * 8;
    const int sk = (l4 >> 1) & 3;
    const unsigned short* Ar0 = A + (size_t)(m0 + r0) * lda + kk;
    const unsigned short* Br0 = Bt + (size_t)(n0 + r0) * ldb + kk;
    const unsigned short* Br1 = Bt + (size_t)(n0 + 64 + r0) * ldb + kk;
    auto stage = [&](int sb, int k0) {
        gload_lds16(Ar0 + k0, (char*)As[sb] + tid * 16);
        gload_lds16(Br0 + k0, (char*)Bs[sb] + tid * 16);
        gload_lds16(Br1 + k0, (char*)Bs[sb] + 4096 + tid * 16);
    };
    const int nk = Kloop >> 5;
    stage(0, 0);
    stage(1, 32);
    asm volatile("s_waitcnt vmcnt(3)" ::: "memory");
    __builtin_amdgcn_s_barrier();
    asm volatile("" ::: "memory");
    int buf = 0;
    for (int t = 0; t < nk; ++t) {
        if (t + 2 < nk) {
            int b2 = buf + 2; if (b2 >= 3) b2 -= 3;
            stage(b2, (t + 2) * 32);
        }
        short8 a[4], b[2];
#pragma unroll
        for (int m = 0; m < 4; m++)
            a[m] = *(const short8*)(As[buf] + (m * 16 + l4) * 32 + (g ^ sk) * 8);
#pragma unroll
        for (int n = 0; n < 2; n++)
            b[n] = *(const short8*)(Bs[buf] + (w * 32 + n * 16 + l4) * 32 + (g ^ sk) * 8);
#pragma unroll
        for (int m = 0; m < 4; m++)
#pragma unroll
            for (int n = 0; n < 2; n++)
                acc[m][n] = __builtin_amdgcn_mfma_f32_16x16x32_bf16(a[m], b[n], acc[m][n], 0, 0, 0);
        if (t + 1 < nk) {
            if (t + 2 < nk) asm volatile("s_waitcnt vmcnt(3)" ::: "memory");
            else            asm volatile("s_waitcnt vmcnt(0)" ::: "memory");
            __builtin_amdgcn_s_barrier();
            asm volatile("" ::: "memory");
        }
        buf = (buf + 1 == 3) ? 0 : buf + 1;
    }
    const int rowB = m0 + g * 4;
    const int colB = n0 + w * 32 + l4;
#pragma unroll
    for (int n = 0; n < 2; n++) {
        float bv = bias[colB + n * 16];
#pragma unroll
        for (int m = 0; m < 4; m++) {
#pragma unroll
            for (int r = 0; r < 4; r++) {
                float v = acc[m][n][r] + bv;
                if (EPI == 2) v = fmaxf(v, 0.f);
                size_t idx = (size_t)(rowB + m * 16 + r) * N + colB + n * 16;
                if (EPI == 1) outF[idx] = v;
                else outB[idx] = f2bf(v);
            }
        }
    }
}

// ---------------- flash attention v6: 8 waves / 128 q-rows per block ----------------
template <int CAUSAL>
__global__ __launch_bounds__(512) void attn6_kernel(const unsigned short* __restrict__ Q, int ldq,
                                                    const unsigned short* __restrict__ Kg, int ldk,
                                                    const unsigned short* __restrict__ Vt,
                                                    unsigned short* __restrict__ O) {
    __shared__ unsigned short Kl[2 * 64 * 64];
    __shared__ unsigned short Vl[2 * 64 * 64];
    __shared__ unsigned short Pl[8][16 * 72];
    const int bh = blockIdx.x;
    const int qb = CAUSAL ? (gridDim.y - 1 - blockIdx.y) : blockIdx.y;
    const int b = bh >> 4, h = bh & 15;
    const int tid = threadIdx.x, w = tid >> 6, lane = tid & 63;
    const int l4 = lane & 15, g = lane >> 4;
    const int q0 = qb * 128 + w * 16;
    const unsigned short* Qp = Q + (size_t)(b * Tc + q0 + l4) * ldq + h * DHc + g * 8;
    short8 qf0 = *(const short8*)Qp;
    short8 qf1 = *(const short8*)(Qp + 32);
    const unsigned short* Kbase = Kg + (size_t)(b * 1024) * ldk + h * DHc;
    const unsigned short* Vbase = Vt + (size_t)bh * DHc * 1024;
    f32x4 o[4] = {};
    float mrun = -1e30f, lrun = 0.f;
    const int nT = CAUSAL ? 2 * qb + 2 : 16;
    unsigned short* pw = &Pl[w][l4 * 72];
    const int qi = q0 + l4;

    short8 ones;
#pragma unroll
    for (int j = 0; j < 8; j++) ones[j] = (short)0x3F80;

    const int sr = tid >> 3;
    const int sc_ = (tid & 7) ^ (sr & 7);

    auto stage = [&](int s0, int buf) {
        char* kd = (char*)Kl + buf * 8192;
        char* vd = (char*)Vl + buf * 8192;
        gload_lds16(Kbase + (size_t)(s0 + sr) * ldk + sc_ * 8, kd + tid * 16);
        gload_lds16(Vbase + (size_t)sr * 1024 + s0 + sc_ * 8, vd + tid * 16);
    };

    stage(0, 0);
    __syncthreads();
    int buf = 0;
    const int sw = l4 & 7;

    for (int t = 0; t < nT; ++t) {
        const int s0 = t * 64;
        if (t + 1 < nT) stage(s0 + 64, buf ^ 1);
        if (!CAUSAL || s0 <= q0 + 15) {
            const unsigned short* Kb_ = Kl + buf * 4096;
            const unsigned short* Vb_ = Vl + buf * 4096;
            f32x4 st[4];
            f32x4 z = {0.f, 0.f, 0.f, 0.f};
            __builtin_amdgcn_s_setprio(1);
#pragma unroll
            for (int c = 0; c < 4; c++) {
                const unsigned short* kr = Kb_ + (c * 16 + l4) * 64;
                short8 ka0 = *(const short8*)(kr + ((g ^ sw) * 8));
                short8 ka1 = *(const short8*)(kr + (((g + 4) ^ sw) * 8));
                st[c] = __builtin_amdgcn_mfma_f32_16x16x32_bf16(ka0, qf0, z, 0, 0, 0);
                st[c] = __builtin_amdgcn_mfma_f32_16x16x32_bf16(ka1, qf1, st[c], 0, 0, 0);
            }
            __builtin_amdgcn_s_setprio(0);
            float p[16];
            const bool domask = CAUSAL && (s0 + 63 > q0);
#pragma unroll
            for (int c = 0; c < 4; c++)
#pragma unroll
                for (int r = 0; r < 4; r++) {
                    float v = st[c][r];
                    if (domask && (s0 + c * 16 + g * 4 + r) > qi) v = -1e9f;
                    p[c * 4 + r] = v;
                }
            float m1 = fmaxf(fmaxf(p[0], p[1]), p[2]);
            float m2 = fmaxf(fmaxf(p[3], p[4]), p[5]);
            float m3 = fmaxf(fmaxf(p[6], p[7]), p[8]);
            float m4 = fmaxf(fmaxf(p[9], p[10]), p[11]);
            float m5 = fmaxf(fmaxf(p[12], p[13]), p[14]);
            float tmax = fmaxf(fmaxf(fmaxf(m1, m2), fmaxf(m3, m4)), fmaxf(m5, p[15]));
            tmax = fmaxf(tmax, __shfl_xor(tmax, 16));
            tmax = fmaxf(tmax, __shfl_xor(tmax, 32));
            if (!__all(tmax <= mrun + 11.5f)) {
                float mnew = fmaxf(mrun, tmax);
                float al = fexp2(mrun - mnew);
                lrun *= al;
#pragma unroll
                for (int d = 0; d < 4; d++) o[d] *= al;
                mrun = mnew;
            }
#pragma unroll
            for (int i = 0; i < 16; i++) p[i] = fexp2(p[i] - mrun);
#pragma unroll
            for (int c = 0; c < 4; c++) {
                uint2 u;
                u.x = cvtpk(p[c * 4 + 0], p[c * 4 + 1]);
                u.y = cvtpk(p[c * 4 + 2], p[c * 4 + 3]);
                *(uint2*)(pw + c * 16 + g * 4) = u;
            }
            short8 pb_lo = *(const short8*)(pw + g * 8);
            short8 pb_hi = *(const short8*)(pw + 32 + g * 8);
            __builtin_amdgcn_s_setprio(1);
            f32x4 s4 = __builtin_amdgcn_mfma_f32_16x16x32_bf16(ones, pb_lo, z, 0, 0, 0);
            s4 = __builtin_amdgcn_mfma_f32_16x16x32_bf16(ones, pb_hi, s4, 0, 0, 0);
#pragma unroll
            for (int d = 0; d < 4; d++) {
                const unsigned short* vr = Vb_ + (d * 16 + l4) * 64;
                short8 va0 = *(const short8*)(vr + ((g ^ sw) * 8));
                short8 va1 = *(const short8*)(vr + (((g + 4) ^ sw) * 8));
                o[d] = __builtin_amdgcn_mfma_f32_16x16x32_bf16(va0, pb_lo, o[d], 0, 0, 0);
                o[d] = __builtin_amdgcn_mfma_f32_16x16x32_bf16(va1, pb_hi, o[d], 0, 0, 0);
            }
            __builtin_amdgcn_s_setprio(0);
            lrun += s4[0];
        }
        __syncthreads();
        buf ^= 1;
    }
    float inv = 1.f / lrun;
    unsigned short* Ob = O + (size_t)(b * Tc + q0 + l4) * Dc + h * DHc;
#pragma unroll
    for (int d = 0; d < 4; d++) {
#pragma unroll
        for (int r = 0; r < 4; r++) Ob[d * 16 + g * 4 + r] = f2bf(o[d][r] * inv);
    }
}

// ---------------- fused residual-add + LayerNorm (bf16 a + bf16 res) ----------------
__global__ __launch_bounds__(256) void ln_bf(const unsigned short* __restrict__ a,
                                             const unsigned short* __restrict__ res,
                                             const float* __restrict__ gam,
                                             const float* __restrict__ bet,
                                             unsigned short* __restrict__ outB,
                                             float* __restrict__ outF) {
    int row = blockIdx.x, t = threadIdx.x;
    size_t base = (size_t)row * Dc + t * 4;
    short4v av = *(const short4v*)(a + base);
    short4v rv = *(const short4v*)(res + base);
    float x0 = bf2f((unsigned short)av[0]) + bf2f((unsigned short)rv[0]);
    float x1 = bf2f((unsigned short)av[1]) + bf2f((unsigned short)rv[1]);
    float x2 = bf2f((unsigned short)av[2]) + bf2f((unsigned short)rv[2]);
    float x3 = bf2f((unsigned short)av[3]) + bf2f((unsigned short)rv[3]);
    float s = x0 + x1 + x2 + x3;
    float ss = x0 * x0 + x1 * x1 + x2 * x2 + x3 * x3;
    for (int o = 1; o < 64; o <<= 1) { s += __shfl_xor(s, o); ss += __shfl_xor(ss, o); }
    __shared__ float S1[4], S2[4];
    int w = t >> 6;
    if ((t & 63) == 0) { S1[w] = s; S2[w] = ss; }
    __syncthreads();
    s = S1[0] + S1[1] + S1[2] + S1[3];
    ss = S2[0] + S2[1] + S2[2] + S2[3];
    float mean = s * (1.f / Dc);
    float var = ss * (1.f / Dc) - mean * mean;
    float rstd = rsqrtf(var + 1e-5f);
    int c = t * 4;
    float4 g4 = *(const float4*)(gam + c);
    float4 b4 = *(const float4*)(bet + c);
    float y0 = (x0 - mean) * rstd * g4.x + b4.x;
    float y1 = (x1 - mean) * rstd * g4.y + b4.y;
    float y2 = (x2 - mean) * rstd * g4.z + b4.z;
    float y3 = (x3 - mean) * rstd * g4.w + b4.w;
    if (outB) {
        short4v ob;
        ob[0] = f2bf(y0); ob[1] = f2bf(y1); ob[2] = f2bf(y2); ob[3] = f2bf(y3);
        *(short4v*)(outB + base) = ob;
    }
    if (outF) { float4 ov = {y0, y1, y2, y3}; *(float4*)(outF + base) = ov; }
}

// ---------------- LN over 4 bf16 split-K partials + bf16 residual -> f32 out ----------------
__global__ __launch_bounds__(256) void ln_4b(const unsigned short* __restrict__ p,
                                             const unsigned short* __restrict__ res,
                                             const float* __restrict__ gam,
                                             const float* __restrict__ bet,
                                             float* __restrict__ outF) {
    const size_t PS = (size_t)4096 * 1024;
    int row = blockIdx.x, t = threadIdx.x;
    size_t base = (size_t)row * Dc + t * 4;
    float x0, x1, x2, x3;
    {
        short4v rv = *(const short4v*)(res + base);
        x0 = bf2f((unsigned short)rv[0]); x1 = bf2f((unsigned short)rv[1]);
        x2 = bf2f((unsigned short)rv[2]); x3 = bf2f((unsigned short)rv[3]);
    }
#pragma unroll
    for (int j = 0; j < 4; j++) {
        short4v v = *(const short4v*)(p + j * PS + base);
        x0 += bf2f((unsigned short)v[0]); x1 += bf2f((unsigned short)v[1]);
        x2 += bf2f((unsigned short)v[2]); x3 += bf2f((unsigned short)v[3]);
    }
    float s = x0 + x1 + x2 + x3;
    float ss = x0 * x0 + x1 * x1 + x2 * x2 + x3 * x3;
    for (int o = 1; o < 64; o <<= 1) { s += __shfl_xor(s, o); ss += __shfl_xor(ss, o); }
    __shared__ float S1[4], S2[4];
    int w = t >> 6;
    if ((t & 63) == 0) { S1[w] = s; S2[w] = ss; }
    __syncthreads();
    s = S1[0] + S1[1] + S1[2] + S1[3];
    ss = S2[0] + S2[1] + S2[2] + S2[3];
    float mean = s * (1.f / Dc);
    float var = ss * (1.f / Dc) - mean * mean;
    float rstd = rsqrtf(var + 1e-5f);
    int c = t * 4;
    float4 g4 = *(const float4*)(gam + c);
    float4 b4 = *(const float4*)(bet + c);
    float4 ov;
    ov.x = (x0 - mean) * rstd * g4.x + b4.x;
    ov.y = (x1 - mean) * rstd * g4.y + b4.y;
    ov.z = (x2 - mean) * rstd * g4.z + b4.z;
    ov.w = (x3 - mean) * rstd * g4.w + b4.w;
    *(float4*)(outF + base) = ov;
}

// ---------------- launch ----------------
extern "C" void kernel_launch(void* const* d_in, const int* in_sizes, int n_in,
                              void* d_out, int out_size, void* d_ws, size_t ws_size,
                              hipStream_t stream) {
    const float* x   = (const float*)d_in[0];
    const float* enc = (const float*)d_in[1];
    const float* dWq = (const float*)d_in[4];  const float* dbq = (const float*)d_in[5];
    const float* dWk = (const float*)d_in[6];  const float* dbk = (const float*)d_in[7];
    const float* dWv = (const float*)d_in[8];  const float* dbv = (const float*)d_in[9];
    const float* dWo = (const float*)d_in[10]; const float* dbo = (const float*)d_in[11];
    const float* eWq = (const float*)d_in[12]; const float* ebq = (const float*)d_in[13];
    const float* eWk = (const float*)d_in[14]; const float* ebk = (const float*)d_in[15];
    const float* eWv = (const float*)d_in[16]; const float* ebv = (const float*)d_in[17];
    const float* eWo = (const float*)d_in[18]; const float* ebo = (const float*)d_in[19];
    const float* fW1 = (const float*)d_in[20]; const float* fb1 = (const float*)d_in[21];
    const float* fW2 = (const float*)d_in[22]; const float* fb2 = (const float*)d_in[23];
    const float* g1 = (const float*)d_in[24];  const float* be1 = (const float*)d_in[25];
    const float* g2 = (const float*)d_in[26];  const float* be2 = (const float*)d_in[27];
    const float* g3 = (const float*)d_in[28];  const float* be3 = (const float*)d_in[29];

    const float SC = 0.125f * 1.44269504f;

    char* ws = (char*)d_ws;
    size_t off = 0;
    auto alloc = [&](size_t bytes) -> void* {
        void* p = ws + off;
        off += (bytes + 255) & ~(size_t)255;
        return p;
    };
    const size_t A = (size_t)4096 * 1024;
    const size_t MB1 = (size_t)1024 * 1024;
    char* R1 = (char*)alloc(32 * 1024 * 1024);
    unsigned short* qkv = (unsigned short*)R1;                       // stride 3072 (Q,K cols only)
    unsigned short* qx  = (unsigned short*)(R1 + 16 * 1024 * 1024);  // stride 1024
    unsigned short* h1  = (unsigned short*)R1;                       // 4096x4096
    unsigned short* xb   = (unsigned short*)alloc(A * 2);
    unsigned short* encb = (unsigned short*)alloc(A * 2);
    unsigned short* wqkv = (unsigned short*)alloc(3 * MB1 * 2);
    unsigned short* wekv = (unsigned short*)alloc(2 * MB1 * 2);
    unsigned short* weq  = (unsigned short*)alloc(MB1 * 2);
    unsigned short* wdo  = (unsigned short*)alloc(MB1 * 2);
    unsigned short* weo  = (unsigned short*)alloc(MB1 * 2);
    unsigned short* wf1  = (unsigned short*)alloc(4 * MB1 * 2);
    unsigned short* wf2  = (unsigned short*)alloc(4 * MB1 * 2);
    float* bqkv = (float*)alloc(3072 * 4);
    float* bekv = (float*)alloc(2048 * 4);
    float* ebq_s = (float*)alloc(1024 * 4);
    unsigned short* VtB = (unsigned short*)alloc(A * 2);
    unsigned short* ab  = (unsigned short*)alloc(A * 2);
    unsigned short* tmpB = (unsigned short*)alloc(A * 2);
    unsigned short* dB = (unsigned short*)alloc(A * 2);
    unsigned short* fB = (unsigned short*)alloc(A * 2);
    unsigned short* kb  = (unsigned short*)alloc(A * 2);   // cross-K rows (stride 1024)
    unsigned short* vtc = (unsigned short*)alloc(A * 2);   // cross V^T
    unsigned short* pfb = VtB;                             // FFN2 partials alias VtB..dB
    (void)ws_size; (void)in_sizes; (void)n_in; (void)out_size;

    cast2_f32_bf16<<<dim3(2048, 2), 256, 0, stream>>>(x, enc, xb, encb, (int)(A / 8));

    TJ16 tj;
    tj.j[0] = {dWq, wqkv,           1024, 1024, SC};
    tj.j[1] = {dWk, wqkv + MB1,     1024, 1024, 1.f};
    tj.j[2] = {dWv, wqkv + 2 * MB1, 1024, 1024, 1.f};
    tj.j[3] = {eWk, wekv,           1024, 1024, 1.f};
    tj.j[4] = {eWv, wekv + MB1,     1024, 1024, 1.f};
    tj.j[5] = {eWq, weq,            1024, 1024, SC};
    tj.j[6] = {dWo, wdo,            1024, 1024, 1.f};
    tj.j[7] = {eWo, weo,            1024, 1024, 1.f};
    for (int jj = 0; jj < 4; jj++) {
        tj.j[8 + jj]  = {fW1 + 1024 * jj, wf1 + (size_t)1024 * jj * 1024, 4096, 1024, 1.f};
        tj.j[12 + jj] = {fW2 + (size_t)1024 * jj * 1024, wf2 + 1024 * jj, 1024, 4096, 1.f};
    }
    transpose_cast16<<<dim3(16, 16, 16), 256, 0, stream>>>(tj);
    prep_bias<<<24, 256, 0, stream>>>(dbq, dbk, dbv, ebk, ebv, ebq, bqkv, bekv, ebq_s, SC);

    P8 z8{};

    // ---- fused QKV + eKV dispatch (320 blocks) ----
    {
        GJ2 gj;
        gj.j[0] = {xb, wqkv, bqkv, qkv, VtB, 3072, 1024, 1024, 16, 2048, 192, 12};
        gj.j[1] = {encb, wekv, bekv, kb, vtc, 1024, 1024, 1024, 16, 1024, 128, 8};
        gemm256j<<<dim3(320), 512, 0, stream>>>(gj);
    }

    // ---- self-attention block ----
    attn6_kernel<1><<<dim3(64, 8), 512, 0, stream>>>(qkv, 3072, qkv + 1024, 3072, VtB, ab);
    gemm64_db<0><<<dim3(8, 64), 256, 0, stream>>>(ab, wdo, dbo, nullptr, tmpB, 4096, 1024, 1024, 1024, 1024);
    ln_bf<<<4096, 256, 0, stream>>>(tmpB, xb, g1, be1, dB, nullptr);

    // ---- cross-attention block ----
    gemm64_db<0><<<dim3(8, 64), 256, 0, stream>>>(dB, weq, ebq_s, nullptr, qx, 4096, 1024, 1024, 1024, 1024);
    attn6_kernel<0><<<dim3(64, 8), 512, 0, stream>>>(qx, 1024, kb, 1024, vtc, ab);
    gemm64_db<0><<<dim3(8, 64), 256, 0, stream>>>(ab, weo, ebo, nullptr, tmpB, 4096, 1024, 1024, 1024, 1024);
    ln_bf<<<4096, 256, 0, stream>>>(tmpB, dB, g2, be2, fB, nullptr);

    // ---- FFN block (proven 8-phase 256^2 kernels) ----
    gemm256<2><<<dim3(16, 16), 512, 0, stream>>>(fB, wf1, fb1, h1, 4096, 1024, 1024, 16, z8);
    {
        P8 pf{};
        pf.o[0] = pfb;
        pf.o[1] = pfb + A;
        pf.o[2] = pfb + 2 * A;
        pf.o[3] = pfb + 3 * A;
        gemm256<3><<<dim3(4, 16, 4), 512, 0, stream>>>(h1, wf2, fb2, nullptr, 1024, 4096, 4096, 16, pf);
    }
    ln_4b<<<4096, 256, 0, stream>>>(pfb, fB, g3, be3, (float*)d_out);
}